// Round 14
// baseline (114.062 us; speedup 1.0000x reference)
//
#include <hip/hip_runtime.h>

namespace {

constexpr int Tt = 32;    // frames (t)
constexpr int Ss = 784;   // floats per row (h*w)

using bf16x8 = __attribute__((ext_vector_type(8))) short;
using f32x4  = __attribute__((ext_vector_type(4))) float;

// split fp32 -> hi (truncated bf16) + lo (bf16 of residual); pack 2 per uint
__device__ inline void cvt2(float a, float b, unsigned& h, unsigned& l) {
  const unsigned ha = __float_as_uint(a) >> 16;
  const unsigned hb = __float_as_uint(b) >> 16;
  const float ra = a - __uint_as_float(ha << 16);
  const float rb = b - __uint_as_float(hb << 16);
  const unsigned la = __float_as_uint(ra) >> 16;
  const unsigned lb = __float_as_uint(rb) >> 16;
  h = ha | (hb << 16);
  l = la | (lb << 16);
}

// async global->LDS, 16 B per lane; LDS dest must be wave-uniform base.
__device__ inline void gload16(const float* g, float* l) {
  __builtin_amdgcn_global_load_lds(
      (const __attribute__((address_space(1))) void*)g,
      (__attribute__((address_space(3))) void*)l, 16, 0, 0);
}

// ---------------------------------------------------------------------------
// Kernel 1: per-(b,c) Gram via split-bf16 MFMA, direct-global fragments
// (unchanged from rounds 10-13; near its HBM floor).
// ---------------------------------------------------------------------------
__global__ __launch_bounds__(256, 4) void gram_partial(const float* __restrict__ x,
                                                       float* __restrict__ part) {
  const int bc = blockIdx.x;                       // b*64 + c
  const float* __restrict__ xb = x + (size_t)bc * (Tt * Ss);
  const int tid  = threadIdx.x;
  const int w    = tid >> 6;          // wave 0..3
  const int lane = tid & 63;
  const int col  = lane & 15;
  const int g    = lane >> 4;

  f32x4 d1[2][2], d2[2][2], d3[2][2];
#pragma unroll
  for (int i = 0; i < 2; ++i)
#pragma unroll
    for (int j = 0; j < 2; ++j) { d1[i][j] = 0.f; d2[i][j] = 0.f; d3[i][j] = 0.f; }

  const float* __restrict__ pa = xb + (size_t)col * Ss;         // rows 0-15
  const float* __restrict__ pb = xb + (size_t)(16 + col) * Ss;  // rows 16-31

  for (int ks = w; ks < 25; ks += 4) {
    const int s0 = ks * 32 + g * 8;
    uint4 ha = {0u,0u,0u,0u}, la = {0u,0u,0u,0u};
    uint4 hb = {0u,0u,0u,0u}, lb = {0u,0u,0u,0u};
    if (s0 < 784) {
      const float4 a0 = *reinterpret_cast<const float4*>(pa + s0);
      const float4 a1 = *reinterpret_cast<const float4*>(pa + s0 + 4);
      const float4 b0 = *reinterpret_cast<const float4*>(pb + s0);
      const float4 b1 = *reinterpret_cast<const float4*>(pb + s0 + 4);
      cvt2(a0.x, a0.y, ha.x, la.x);
      cvt2(a0.z, a0.w, ha.y, la.y);
      cvt2(a1.x, a1.y, ha.z, la.z);
      cvt2(a1.z, a1.w, ha.w, la.w);
      cvt2(b0.x, b0.y, hb.x, lb.x);
      cvt2(b0.z, b0.w, hb.y, lb.y);
      cvt2(b1.x, b1.y, hb.z, lb.z);
      cvt2(b1.z, b1.w, hb.w, lb.w);
    }
    const bf16x8 h0 = __builtin_bit_cast(bf16x8, ha);
    const bf16x8 l0 = __builtin_bit_cast(bf16x8, la);
    const bf16x8 h1 = __builtin_bit_cast(bf16x8, hb);
    const bf16x8 l1 = __builtin_bit_cast(bf16x8, lb);
    d1[0][0] = __builtin_amdgcn_mfma_f32_16x16x32_bf16(h0, h0, d1[0][0], 0, 0, 0);
    d1[0][1] = __builtin_amdgcn_mfma_f32_16x16x32_bf16(h0, h1, d1[0][1], 0, 0, 0);
    d1[1][0] = __builtin_amdgcn_mfma_f32_16x16x32_bf16(h1, h0, d1[1][0], 0, 0, 0);
    d1[1][1] = __builtin_amdgcn_mfma_f32_16x16x32_bf16(h1, h1, d1[1][1], 0, 0, 0);
    d2[0][0] = __builtin_amdgcn_mfma_f32_16x16x32_bf16(h0, l0, d2[0][0], 0, 0, 0);
    d2[0][1] = __builtin_amdgcn_mfma_f32_16x16x32_bf16(h0, l1, d2[0][1], 0, 0, 0);
    d2[1][0] = __builtin_amdgcn_mfma_f32_16x16x32_bf16(h1, l0, d2[1][0], 0, 0, 0);
    d2[1][1] = __builtin_amdgcn_mfma_f32_16x16x32_bf16(h1, l1, d2[1][1], 0, 0, 0);
    d3[0][0] = __builtin_amdgcn_mfma_f32_16x16x32_bf16(l0, h0, d3[0][0], 0, 0, 0);
    d3[0][1] = __builtin_amdgcn_mfma_f32_16x16x32_bf16(l0, h1, d3[0][1], 0, 0, 0);
    d3[1][0] = __builtin_amdgcn_mfma_f32_16x16x32_bf16(l1, h0, d3[1][0], 0, 0, 0);
    d3[1][1] = __builtin_amdgcn_mfma_f32_16x16x32_bf16(l1, h1, d3[1][1], 0, 0, 0);
  }

  // ---- epilogue: combine D1+D2+D3, reduce over 4 waves (LDS, 1 barrier) ----
  __shared__ float mtmp[4 * 1056];    // 16896 B
#pragma unroll
  for (int i = 0; i < 2; ++i)
#pragma unroll
    for (int j = 0; j < 2; ++j) {
      const f32x4 s4 = d1[i][j] + d2[i][j] + d3[i][j];
#pragma unroll
      for (int r = 0; r < 4; ++r) {
        const int row = i * 16 + g * 4 + r;       // m89-verified C/D map
        const int cc  = j * 16 + col;
        mtmp[w * 1056 + row * 33 + cc] = s4[r];
      }
    }
  __syncthreads();

  const int e0 = tid * 4;
  float tmp[4];
#pragma unroll
  for (int u = 0; u < 4; ++u) {
    const int row = (e0 + u) >> 5;
    const int cc  = (e0 + u) & 31;
    float ss = 0.f;
#pragma unroll
    for (int ww = 0; ww < 4; ++ww) ss += mtmp[ww * 1056 + row * 33 + cc];
    tmp[u] = ss;
  }
  float4 o4;
  o4.x = tmp[0]; o4.y = tmp[1]; o4.z = tmp[2]; o4.w = tmp[3];
  *reinterpret_cast<float4*>(part + (size_t)bc * 1024 + e0) = o4;
}

// ---------------------------------------------------------------------------
// Kernel 2: reduce partials over c.  msum[b][e] = sum_c part[b*64+c][e]
// ---------------------------------------------------------------------------
__global__ __launch_bounds__(256) void reduce_c(const float* __restrict__ part,
                                                float* __restrict__ msum) {
  const int bid = blockIdx.x;                // 0..63
  const int b   = bid >> 2;
  const int e   = (bid & 3) * 256 + threadIdx.x;   // 0..1023
  const float* __restrict__ p = part + (size_t)b * 64 * 1024 + e;
  float s0 = 0.f, s1 = 0.f, s2 = 0.f, s3 = 0.f;
#pragma unroll
  for (int c = 0; c < 64; c += 4) {
    s0 += p[(size_t)(c + 0) * 1024];
    s1 += p[(size_t)(c + 1) * 1024];
    s2 += p[(size_t)(c + 2) * 1024];
    s3 += p[(size_t)(c + 3) * 1024];
  }
  msum[b * 1024 + e] = (s0 + s1) + (s2 + s3);
}

// ---------------------------------------------------------------------------
// Kernel 3: softmax over the BATCH axis + transpose to [k][q]-major.
// ---------------------------------------------------------------------------
__global__ __launch_bounds__(256) void softmax_b(const float* __restrict__ msum,
                                                 float* __restrict__ mt) {
  const int e = blockIdx.x * 256 + threadIdx.x;    // q*32 + k
  float l[16];
  float mx = -3.4e38f;
#pragma unroll
  for (int b = 0; b < 16; ++b) {
    l[b] = msum[b * 1024 + e];
    mx = fmaxf(mx, l[b]);
  }
  float s = 0.f;
#pragma unroll
  for (int b = 0; b < 16; ++b) {
    l[b] = expf(l[b] - mx);
    s += l[b];
  }
  const float inv = 1.f / s;
  const int et = (e & 31) * 32 + (e >> 5);         // k*32 + q
#pragma unroll
  for (int b = 0; b < 16; ++b) mt[b * 1024 + et] = l[b] * inv;
}

// ---------------------------------------------------------------------------
// Kernel 4: PV — one block per bc (contiguous 98 KB writes, no cross-block
// partial-line thrash) + single 25 KB LDS buffer for 6 blocks/CU TLP.
// 1024 blocks x 256 threads (4 waves). Loop ch=0..3: stage(ch) -> barrier ->
// compute(ch) -> barrier. No intra-block double-buffer: the 6 resident
// blocks/CU provide the stage/compute overlap (r13 showed occupancy works;
// r13's regression was the write split, reverted here).
// M in VGPRs via readlane (r12-validated). Inner loop: 1 ds_read_b128 +
// 8 readlane + 32 v_fma per k.
// ---------------------------------------------------------------------------
__global__ __launch_bounds__(256, 6) void pv(const float* __restrict__ xv,
                                             const float* __restrict__ mt,
                                             float* __restrict__ out) {
  const int bc = blockIdx.x;                  // b*64 + c
  const int b  = bc >> 6;
  const float* __restrict__ xvb = xv + (size_t)bc * (Tt * Ss);
  float* __restrict__ ob        = out + (size_t)bc * (Tt * Ss);

  const int tid  = threadIdx.x;
  const int w    = tid >> 6;
  const int lane = tid & 63;
  const int q0   = 8 * w;

  __shared__ float lds[6272];                 // 25088 B -> 6 blocks/CU

  // ---- M into 4 VGPRs/lane (one coalesced float4 load per wave) ----
  const float4 mv = *reinterpret_cast<const float4*>(
      mt + b * 1024 + (lane >> 1) * 32 + q0 + (lane & 1) * 4);
  int mi[4];
  mi[0] = __builtin_bit_cast(int, mv.x);
  mi[1] = __builtin_bit_cast(int, mv.y);
  mi[2] = __builtin_bit_cast(int, mv.z);
  mi[3] = __builtin_bit_cast(int, mv.w);

  for (int ch = 0; ch < 4; ++ch) {
    // ---- stage chunk ch: 32 rows x 196 floats, zero-VGPR async ----
#pragma unroll
    for (int round = 0; round < 6; ++round) {
      const int v   = round * 256 + tid;      // slot = row*49 + c4
      const int row = v / 49;
      const int c4  = v - row * 49;
      gload16(xvb + row * Ss + ch * 196 + c4 * 4,
              &lds[(round * 256 + w * 64) * 4]);
    }
    if (tid < 32) {                           // tail: slots 1536..1567 (wave 0)
      const int v   = 1536 + tid;
      const int row = v / 49;
      const int c4  = v - row * 49;
      gload16(xvb + row * Ss + ch * 196 + c4 * 4, &lds[1536 * 4]);
    }
    __syncthreads();                          // drains vmcnt: chunk staged

    if (lane < 49) {
      const float* __restrict__ lbuf = &lds[0] + lane * 4;
      float4 acc[8] = {};
#pragma unroll
      for (int k = 0; k < 32; ++k) {
        const float4 v = *reinterpret_cast<const float4*>(lbuf + k * 196);
#pragma unroll
        for (int r = 0; r < 8; ++r) {
          const float m = __builtin_bit_cast(
              float, __builtin_amdgcn_readlane(mi[r & 3], 2 * k + (r >> 2)));
          acc[r].x += m * v.x; acc[r].y += m * v.y;
          acc[r].z += m * v.z; acc[r].w += m * v.w;
        }
      }
      float* __restrict__ dst = ob + ch * 196 + 4 * lane;
#pragma unroll
      for (int r = 0; r < 8; ++r)
        *reinterpret_cast<float4*>(dst + (size_t)(q0 + r) * Ss) = acc[r];
    }
    __syncthreads();                          // compute done before restage
  }
}

}  // namespace

extern "C" void kernel_launch(void* const* d_in, const int* in_sizes, int n_in,
                              void* d_out, int out_size, void* d_ws, size_t ws_size,
                              hipStream_t stream) {
  const float* x  = (const float*)d_in[0];
  const float* xv = (const float*)d_in[1];
  float* out = (float*)d_out;

  // workspace (fp32), ~4.2 MiB total:
  float* part = (float*)d_ws;            // 1024 x 1024
  float* msum = part + 1024 * 1024;      // 16 x 1024
  float* mt   = msum + 16 * 1024;        // 16 x 1024 (k-major softmax weights)

  gram_partial<<<dim3(1024), dim3(256), 0, stream>>>(x, part);
  reduce_c<<<dim3(64), dim3(256), 0, stream>>>(part, msum);
  softmax_b<<<dim3(4), dim3(256), 0, stream>>>(msum, mt);
  pv<<<dim3(1024), dim3(256), 0, stream>>>(xv, mt, out);
}

// Round 15
// 79.431 us; speedup vs baseline: 1.4360x; 1.4360x over previous
//
#include <hip/hip_runtime.h>

namespace {

constexpr int Tt = 32;    // frames (t)
constexpr int Ss = 784;   // floats per row (h*w)

using bf16x8 = __attribute__((ext_vector_type(8))) short;
using f32x4  = __attribute__((ext_vector_type(4))) float;

// split fp32 -> hi (truncated bf16) + lo (bf16 of residual); pack 2 per uint
__device__ inline void cvt2(float a, float b, unsigned& h, unsigned& l) {
  const unsigned ha = __float_as_uint(a) >> 16;
  const unsigned hb = __float_as_uint(b) >> 16;
  const float ra = a - __uint_as_float(ha << 16);
  const float rb = b - __uint_as_float(hb << 16);
  const unsigned la = __float_as_uint(ra) >> 16;
  const unsigned lb = __float_as_uint(rb) >> 16;
  h = ha | (hb << 16);
  l = la | (lb << 16);
}

// async global->LDS, 16 B per lane; LDS dest must be wave-uniform base.
__device__ inline void gload16(const float* g, float* l) {
  __builtin_amdgcn_global_load_lds(
      (const __attribute__((address_space(1))) void*)g,
      (__attribute__((address_space(3))) void*)l, 16, 0, 0);
}

// ---------------------------------------------------------------------------
// Kernel 1: per-(b,c) Gram via split-bf16 MFMA, direct-global fragments
// (unchanged from rounds 10-14; near its HBM floor).
// ---------------------------------------------------------------------------
__global__ __launch_bounds__(256, 4) void gram_partial(const float* __restrict__ x,
                                                       float* __restrict__ part) {
  const int bc = blockIdx.x;                       // b*64 + c
  const float* __restrict__ xb = x + (size_t)bc * (Tt * Ss);
  const int tid  = threadIdx.x;
  const int w    = tid >> 6;          // wave 0..3
  const int lane = tid & 63;
  const int col  = lane & 15;
  const int g    = lane >> 4;

  f32x4 d1[2][2], d2[2][2], d3[2][2];
#pragma unroll
  for (int i = 0; i < 2; ++i)
#pragma unroll
    for (int j = 0; j < 2; ++j) { d1[i][j] = 0.f; d2[i][j] = 0.f; d3[i][j] = 0.f; }

  const float* __restrict__ pa = xb + (size_t)col * Ss;         // rows 0-15
  const float* __restrict__ pb = xb + (size_t)(16 + col) * Ss;  // rows 16-31

  for (int ks = w; ks < 25; ks += 4) {
    const int s0 = ks * 32 + g * 8;
    uint4 ha = {0u,0u,0u,0u}, la = {0u,0u,0u,0u};
    uint4 hb = {0u,0u,0u,0u}, lb = {0u,0u,0u,0u};
    if (s0 < 784) {
      const float4 a0 = *reinterpret_cast<const float4*>(pa + s0);
      const float4 a1 = *reinterpret_cast<const float4*>(pa + s0 + 4);
      const float4 b0 = *reinterpret_cast<const float4*>(pb + s0);
      const float4 b1 = *reinterpret_cast<const float4*>(pb + s0 + 4);
      cvt2(a0.x, a0.y, ha.x, la.x);
      cvt2(a0.z, a0.w, ha.y, la.y);
      cvt2(a1.x, a1.y, ha.z, la.z);
      cvt2(a1.z, a1.w, ha.w, la.w);
      cvt2(b0.x, b0.y, hb.x, lb.x);
      cvt2(b0.z, b0.w, hb.y, lb.y);
      cvt2(b1.x, b1.y, hb.z, lb.z);
      cvt2(b1.z, b1.w, hb.w, lb.w);
    }
    const bf16x8 h0 = __builtin_bit_cast(bf16x8, ha);
    const bf16x8 l0 = __builtin_bit_cast(bf16x8, la);
    const bf16x8 h1 = __builtin_bit_cast(bf16x8, hb);
    const bf16x8 l1 = __builtin_bit_cast(bf16x8, lb);
    d1[0][0] = __builtin_amdgcn_mfma_f32_16x16x32_bf16(h0, h0, d1[0][0], 0, 0, 0);
    d1[0][1] = __builtin_amdgcn_mfma_f32_16x16x32_bf16(h0, h1, d1[0][1], 0, 0, 0);
    d1[1][0] = __builtin_amdgcn_mfma_f32_16x16x32_bf16(h1, h0, d1[1][0], 0, 0, 0);
    d1[1][1] = __builtin_amdgcn_mfma_f32_16x16x32_bf16(h1, h1, d1[1][1], 0, 0, 0);
    d2[0][0] = __builtin_amdgcn_mfma_f32_16x16x32_bf16(h0, l0, d2[0][0], 0, 0, 0);
    d2[0][1] = __builtin_amdgcn_mfma_f32_16x16x32_bf16(h0, l1, d2[0][1], 0, 0, 0);
    d2[1][0] = __builtin_amdgcn_mfma_f32_16x16x32_bf16(h1, l0, d2[1][0], 0, 0, 0);
    d2[1][1] = __builtin_amdgcn_mfma_f32_16x16x32_bf16(h1, l1, d2[1][1], 0, 0, 0);
    d3[0][0] = __builtin_amdgcn_mfma_f32_16x16x32_bf16(l0, h0, d3[0][0], 0, 0, 0);
    d3[0][1] = __builtin_amdgcn_mfma_f32_16x16x32_bf16(l0, h1, d3[0][1], 0, 0, 0);
    d3[1][0] = __builtin_amdgcn_mfma_f32_16x16x32_bf16(l1, h0, d3[1][0], 0, 0, 0);
    d3[1][1] = __builtin_amdgcn_mfma_f32_16x16x32_bf16(l1, h1, d3[1][1], 0, 0, 0);
  }

  // ---- epilogue: combine D1+D2+D3, reduce over 4 waves (LDS, 1 barrier) ----
  __shared__ float mtmp[4 * 1056];    // 16896 B
#pragma unroll
  for (int i = 0; i < 2; ++i)
#pragma unroll
    for (int j = 0; j < 2; ++j) {
      const f32x4 s4 = d1[i][j] + d2[i][j] + d3[i][j];
#pragma unroll
      for (int r = 0; r < 4; ++r) {
        const int row = i * 16 + g * 4 + r;       // m89-verified C/D map
        const int cc  = j * 16 + col;
        mtmp[w * 1056 + row * 33 + cc] = s4[r];
      }
    }
  __syncthreads();

  const int e0 = tid * 4;
  float tmp[4];
#pragma unroll
  for (int u = 0; u < 4; ++u) {
    const int row = (e0 + u) >> 5;
    const int cc  = (e0 + u) & 31;
    float ss = 0.f;
#pragma unroll
    for (int ww = 0; ww < 4; ++ww) ss += mtmp[ww * 1056 + row * 33 + cc];
    tmp[u] = ss;
  }
  float4 o4;
  o4.x = tmp[0]; o4.y = tmp[1]; o4.z = tmp[2]; o4.w = tmp[3];
  *reinterpret_cast<float4*>(part + (size_t)bc * 1024 + e0) = o4;
}

// ---------------------------------------------------------------------------
// Kernel 2: reduce partials over c.  msum[b][e] = sum_c part[b*64+c][e]
// ---------------------------------------------------------------------------
__global__ __launch_bounds__(256) void reduce_c(const float* __restrict__ part,
                                                float* __restrict__ msum) {
  const int bid = blockIdx.x;                // 0..63
  const int b   = bid >> 2;
  const int e   = (bid & 3) * 256 + threadIdx.x;   // 0..1023
  const float* __restrict__ p = part + (size_t)b * 64 * 1024 + e;
  float s0 = 0.f, s1 = 0.f, s2 = 0.f, s3 = 0.f;
#pragma unroll
  for (int c = 0; c < 64; c += 4) {
    s0 += p[(size_t)(c + 0) * 1024];
    s1 += p[(size_t)(c + 1) * 1024];
    s2 += p[(size_t)(c + 2) * 1024];
    s3 += p[(size_t)(c + 3) * 1024];
  }
  msum[b * 1024 + e] = (s0 + s1) + (s2 + s3);
}

// ---------------------------------------------------------------------------
// Kernel 3: softmax over the BATCH axis + transpose to [k][q]-major.
// ---------------------------------------------------------------------------
__global__ __launch_bounds__(256) void softmax_b(const float* __restrict__ msum,
                                                 float* __restrict__ mt) {
  const int e = blockIdx.x * 256 + threadIdx.x;    // q*32 + k
  float l[16];
  float mx = -3.4e38f;
#pragma unroll
  for (int b = 0; b < 16; ++b) {
    l[b] = msum[b * 1024 + e];
    mx = fmaxf(mx, l[b]);
  }
  float s = 0.f;
#pragma unroll
  for (int b = 0; b < 16; ++b) {
    l[b] = expf(l[b] - mx);
    s += l[b];
  }
  const float inv = 1.f / s;
  const int et = (e & 31) * 32 + (e >> 5);         // k*32 + q
#pragma unroll
  for (int b = 0; b < 16; ++b) mt[b * 1024 + et] = l[b] * inv;
}

// ---------------------------------------------------------------------------
// Kernel 4: PV — r13's high-TLP structure with the VGPR strangulation fixed.
// 4096 blocks = bc*4 + s-chunk; 256 threads (4 waves); LDS 25088 B -> up to
// 6 blocks/CU. __launch_bounds__(256,4): VGPR cap 128, so acc[8] (32 regs) +
// staging/addr regs fit WITHOUT SPILL (r13/r14 at (256,6) forced VGPR=40 ->
// scratch spill -> +100 MB on both FETCH and WRITE; that was the regression,
// not the write split: r13 212 vs r14 200 MB writes shows the split costs
// only ~6%). Per block: one 25 KB zero-VGPR async stage -> 1 barrier ->
// compute -> contiguous 784 B-run stores. TLP (6 blocks/CU) overlaps one
// block's stage with five others' compute.
// M in VGPRs via readlane (r12-validated). Inner loop: 1 ds_read_b128 +
// 8 readlane + 32 v_fma per k.
// ---------------------------------------------------------------------------
__global__ __launch_bounds__(256, 4) void pv(const float* __restrict__ xv,
                                             const float* __restrict__ mt,
                                             float* __restrict__ out) {
  const int gbl = blockIdx.x;                 // bc*4 + ch
  const int bc  = gbl >> 2;
  const int ch  = gbl & 3;
  const int b   = bc >> 6;
  const float* __restrict__ xvb = xv + (size_t)bc * (Tt * Ss);
  float* __restrict__ ob        = out + (size_t)bc * (Tt * Ss);

  const int tid  = threadIdx.x;
  const int w    = tid >> 6;
  const int lane = tid & 63;
  const int q0   = 8 * w;

  __shared__ float lds[6272];                 // 25088 B

  // ---- M into 4 VGPRs/lane (one coalesced float4 load per wave) ----
  const float4 mv = *reinterpret_cast<const float4*>(
      mt + b * 1024 + (lane >> 1) * 32 + q0 + (lane & 1) * 4);
  int mi[4];
  mi[0] = __builtin_bit_cast(int, mv.x);
  mi[1] = __builtin_bit_cast(int, mv.y);
  mi[2] = __builtin_bit_cast(int, mv.z);
  mi[3] = __builtin_bit_cast(int, mv.w);

  // ---- stage this block's 32 x 196-float chunk (zero-VGPR async) ----
#pragma unroll
  for (int round = 0; round < 6; ++round) {
    const int v   = round * 256 + tid;        // slot = row*49 + c4
    const int row = v / 49;
    const int c4  = v - row * 49;
    gload16(xvb + row * Ss + ch * 196 + c4 * 4,
            &lds[(round * 256 + w * 64) * 4]);
  }
  if (tid < 32) {                             // tail: slots 1536..1567 (wave 0)
    const int v   = 1536 + tid;
    const int row = v / 49;
    const int c4  = v - row * 49;
    gload16(xvb + row * Ss + ch * 196 + c4 * 4, &lds[1536 * 4]);
  }
  __syncthreads();                            // drains vmcnt: chunk staged

  if (lane < 49) {
    const float* __restrict__ lbuf = &lds[0] + lane * 4;
    float4 acc[8] = {};
#pragma unroll
    for (int k = 0; k < 32; ++k) {
      const float4 v = *reinterpret_cast<const float4*>(lbuf + k * 196);
#pragma unroll
      for (int r = 0; r < 8; ++r) {
        const float m = __builtin_bit_cast(
            float, __builtin_amdgcn_readlane(mi[r & 3], 2 * k + (r >> 2)));
        acc[r].x += m * v.x; acc[r].y += m * v.y;
        acc[r].z += m * v.z; acc[r].w += m * v.w;
      }
    }
    float* __restrict__ dst = ob + ch * 196 + 4 * lane;
#pragma unroll
    for (int r = 0; r < 8; ++r)
      *reinterpret_cast<float4*>(dst + (size_t)(q0 + r) * Ss) = acc[r];
  }
}

}  // namespace

extern "C" void kernel_launch(void* const* d_in, const int* in_sizes, int n_in,
                              void* d_out, int out_size, void* d_ws, size_t ws_size,
                              hipStream_t stream) {
  const float* x  = (const float*)d_in[0];
  const float* xv = (const float*)d_in[1];
  float* out = (float*)d_out;

  // workspace (fp32), ~4.2 MiB total:
  float* part = (float*)d_ws;            // 1024 x 1024
  float* msum = part + 1024 * 1024;      // 16 x 1024
  float* mt   = msum + 16 * 1024;        // 16 x 1024 (k-major softmax weights)

  gram_partial<<<dim3(1024), dim3(256), 0, stream>>>(x, part);
  reduce_c<<<dim3(64), dim3(256), 0, stream>>>(part, msum);
  softmax_b<<<dim3(4), dim3(256), 0, stream>>>(msum, mt);
  pv<<<dim3(4096), dim3(256), 0, stream>>>(xv, mt, out);
}

// Round 16
// 77.844 us; speedup vs baseline: 1.4653x; 1.0204x over previous
//
#include <hip/hip_runtime.h>

namespace {

constexpr int Tt = 32;    // frames (t)
constexpr int Ss = 784;   // floats per row (h*w)

using bf16x8 = __attribute__((ext_vector_type(8))) short;
using f32x4  = __attribute__((ext_vector_type(4))) float;

// split fp32 -> hi (truncated bf16) + lo (bf16 of residual); pack 2 per uint
__device__ inline void cvt2(float a, float b, unsigned& h, unsigned& l) {
  const unsigned ha = __float_as_uint(a) >> 16;
  const unsigned hb = __float_as_uint(b) >> 16;
  const float ra = a - __uint_as_float(ha << 16);
  const float rb = b - __uint_as_float(hb << 16);
  const unsigned la = __float_as_uint(ra) >> 16;
  const unsigned lb = __float_as_uint(rb) >> 16;
  h = ha | (hb << 16);
  l = la | (lb << 16);
}

// async global->LDS, 16 B per lane; LDS dest must be wave-uniform base.
__device__ inline void gload16(const float* g, float* l) {
  __builtin_amdgcn_global_load_lds(
      (const __attribute__((address_space(1))) void*)g,
      (__attribute__((address_space(3))) void*)l, 16, 0, 0);
}

// ---------------------------------------------------------------------------
// Kernel 1: per-(b,c) Gram via split-bf16 MFMA, direct-global fragments
// (unchanged from rounds 10-15; near its HBM floor, ~14-16 us).
// ---------------------------------------------------------------------------
__global__ __launch_bounds__(256, 4) void gram_partial(const float* __restrict__ x,
                                                       float* __restrict__ part) {
  const int bc = blockIdx.x;                       // b*64 + c
  const float* __restrict__ xb = x + (size_t)bc * (Tt * Ss);
  const int tid  = threadIdx.x;
  const int w    = tid >> 6;          // wave 0..3
  const int lane = tid & 63;
  const int col  = lane & 15;
  const int g    = lane >> 4;

  f32x4 d1[2][2], d2[2][2], d3[2][2];
#pragma unroll
  for (int i = 0; i < 2; ++i)
#pragma unroll
    for (int j = 0; j < 2; ++j) { d1[i][j] = 0.f; d2[i][j] = 0.f; d3[i][j] = 0.f; }

  const float* __restrict__ pa = xb + (size_t)col * Ss;         // rows 0-15
  const float* __restrict__ pb = xb + (size_t)(16 + col) * Ss;  // rows 16-31

  for (int ks = w; ks < 25; ks += 4) {
    const int s0 = ks * 32 + g * 8;
    uint4 ha = {0u,0u,0u,0u}, la = {0u,0u,0u,0u};
    uint4 hb = {0u,0u,0u,0u}, lb = {0u,0u,0u,0u};
    if (s0 < 784) {
      const float4 a0 = *reinterpret_cast<const float4*>(pa + s0);
      const float4 a1 = *reinterpret_cast<const float4*>(pa + s0 + 4);
      const float4 b0 = *reinterpret_cast<const float4*>(pb + s0);
      const float4 b1 = *reinterpret_cast<const float4*>(pb + s0 + 4);
      cvt2(a0.x, a0.y, ha.x, la.x);
      cvt2(a0.z, a0.w, ha.y, la.y);
      cvt2(a1.x, a1.y, ha.z, la.z);
      cvt2(a1.z, a1.w, ha.w, la.w);
      cvt2(b0.x, b0.y, hb.x, lb.x);
      cvt2(b0.z, b0.w, hb.y, lb.y);
      cvt2(b1.x, b1.y, hb.z, lb.z);
      cvt2(b1.z, b1.w, hb.w, lb.w);
    }
    const bf16x8 h0 = __builtin_bit_cast(bf16x8, ha);
    const bf16x8 l0 = __builtin_bit_cast(bf16x8, la);
    const bf16x8 h1 = __builtin_bit_cast(bf16x8, hb);
    const bf16x8 l1 = __builtin_bit_cast(bf16x8, lb);
    d1[0][0] = __builtin_amdgcn_mfma_f32_16x16x32_bf16(h0, h0, d1[0][0], 0, 0, 0);
    d1[0][1] = __builtin_amdgcn_mfma_f32_16x16x32_bf16(h0, h1, d1[0][1], 0, 0, 0);
    d1[1][0] = __builtin_amdgcn_mfma_f32_16x16x32_bf16(h1, h0, d1[1][0], 0, 0, 0);
    d1[1][1] = __builtin_amdgcn_mfma_f32_16x16x32_bf16(h1, h1, d1[1][1], 0, 0, 0);
    d2[0][0] = __builtin_amdgcn_mfma_f32_16x16x32_bf16(h0, l0, d2[0][0], 0, 0, 0);
    d2[0][1] = __builtin_amdgcn_mfma_f32_16x16x32_bf16(h0, l1, d2[0][1], 0, 0, 0);
    d2[1][0] = __builtin_amdgcn_mfma_f32_16x16x32_bf16(h1, l0, d2[1][0], 0, 0, 0);
    d2[1][1] = __builtin_amdgcn_mfma_f32_16x16x32_bf16(h1, l1, d2[1][1], 0, 0, 0);
    d3[0][0] = __builtin_amdgcn_mfma_f32_16x16x32_bf16(l0, h0, d3[0][0], 0, 0, 0);
    d3[0][1] = __builtin_amdgcn_mfma_f32_16x16x32_bf16(l0, h1, d3[0][1], 0, 0, 0);
    d3[1][0] = __builtin_amdgcn_mfma_f32_16x16x32_bf16(l1, h0, d3[1][0], 0, 0, 0);
    d3[1][1] = __builtin_amdgcn_mfma_f32_16x16x32_bf16(l1, h1, d3[1][1], 0, 0, 0);
  }

  // ---- epilogue: combine D1+D2+D3, reduce over 4 waves (LDS, 1 barrier) ----
  __shared__ float mtmp[4 * 1056];    // 16896 B
#pragma unroll
  for (int i = 0; i < 2; ++i)
#pragma unroll
    for (int j = 0; j < 2; ++j) {
      const f32x4 s4 = d1[i][j] + d2[i][j] + d3[i][j];
#pragma unroll
      for (int r = 0; r < 4; ++r) {
        const int row = i * 16 + g * 4 + r;       // m89-verified C/D map
        const int cc  = j * 16 + col;
        mtmp[w * 1056 + row * 33 + cc] = s4[r];
      }
    }
  __syncthreads();

  const int e0 = tid * 4;
  float tmp[4];
#pragma unroll
  for (int u = 0; u < 4; ++u) {
    const int row = (e0 + u) >> 5;
    const int cc  = (e0 + u) & 31;
    float ss = 0.f;
#pragma unroll
    for (int ww = 0; ww < 4; ++ww) ss += mtmp[ww * 1056 + row * 33 + cc];
    tmp[u] = ss;
  }
  float4 o4;
  o4.x = tmp[0]; o4.y = tmp[1]; o4.z = tmp[2]; o4.w = tmp[3];
  *reinterpret_cast<float4*>(part + (size_t)bc * 1024 + e0) = o4;
}

// ---------------------------------------------------------------------------
// Kernel 2: reduce partials over c.  msum[b][e] = sum_c part[b*64+c][e]
// ---------------------------------------------------------------------------
__global__ __launch_bounds__(256) void reduce_c(const float* __restrict__ part,
                                                float* __restrict__ msum) {
  const int bid = blockIdx.x;                // 0..63
  const int b   = bid >> 2;
  const int e   = (bid & 3) * 256 + threadIdx.x;   // 0..1023
  const float* __restrict__ p = part + (size_t)b * 64 * 1024 + e;
  float s0 = 0.f, s1 = 0.f, s2 = 0.f, s3 = 0.f;
#pragma unroll
  for (int c = 0; c < 64; c += 4) {
    s0 += p[(size_t)(c + 0) * 1024];
    s1 += p[(size_t)(c + 1) * 1024];
    s2 += p[(size_t)(c + 2) * 1024];
    s3 += p[(size_t)(c + 3) * 1024];
  }
  msum[b * 1024 + e] = (s0 + s1) + (s2 + s3);
}

// ---------------------------------------------------------------------------
// Kernel 3: softmax over the BATCH axis. Output q-major: mq[b][q*32+k].
// ---------------------------------------------------------------------------
__global__ __launch_bounds__(256) void softmax_b(const float* __restrict__ msum,
                                                 float* __restrict__ mq) {
  const int e = blockIdx.x * 256 + threadIdx.x;    // q*32 + k
  float l[16];
  float mx = -3.4e38f;
#pragma unroll
  for (int b = 0; b < 16; ++b) {
    l[b] = msum[b * 1024 + e];
    mx = fmaxf(mx, l[b]);
  }
  float s = 0.f;
#pragma unroll
  for (int b = 0; b < 16; ++b) {
    l[b] = expf(l[b] - mx);
    s += l[b];
  }
  const float inv = 1.f / s;
#pragma unroll
  for (int b = 0; b < 16; ++b) mq[b * 1024 + e] = l[b] * inv;
}

// ---------------------------------------------------------------------------
// Kernel 4: PV via split-bf16 MFMA — r9's VALIDATED fragment math fed by
// r15's VALIDATED zero-VGPR gload_lds staging + 4096-block TLP.
// Grid 4096 = bc*4 + ch; chunk offsets {0,192,384,576} floats (128B-aligned);
// EVERY block stages 208 floats/row (52 float4 slots; overlaps next chunk by
// 16 floats for ch<3 -> uniform staging, ~8% extra fetch, L2-absorbed).
// LDS 32 x 208 fp32 = 26624 B -> 6 blocks/CU. One barrier per block.
// nfrag = 12 (ch<3) or 13 (ch==3): all frags full 16 cols -> NO masking.
// Per frag per lane (col,g): 8 ds_read_b32 v[8g+j][sf*16+col] (4-way bank
// conflict on g -- unavoidable with linear gload layout, 1.58x on 8 cheap
// instrs), cvt -> vh/vl, 6 MFMA (2 qf x {mh*vl, ml*vh, mh*vh}), 8 stores
// (each 4 x 64B segments). M-frags built once per block from q-major mq.
// VALU/block ~1K cyc vs r15-fp32's ~12K -> memory-bound.
// ---------------------------------------------------------------------------
__global__ __launch_bounds__(256, 4) void pv(const float* __restrict__ xv,
                                             const float* __restrict__ mq,
                                             float* __restrict__ out) {
  const int gbl = blockIdx.x;                 // bc*4 + ch
  const int bc  = gbl >> 2;
  const int ch  = gbl & 3;
  const int b   = bc >> 6;
  const int off = ch * 192;                   // chunk start (floats)
  const float* __restrict__ xvb = xv + (size_t)bc * (Tt * Ss);
  float* __restrict__ ob        = out + (size_t)bc * (Tt * Ss);

  const int tid  = threadIdx.x;
  const int w    = tid >> 6;                  // wave 0..3
  const int lane = tid & 63;
  const int col  = lane & 15;                 // frag column / M row
  const int g    = lane >> 4;                 // k-group (k = 8g..8g+7)

  __shared__ float lds[32 * 208];             // 26624 B

  // ---- M fragments (once per block; mq is L2-hot) — r9-validated ----
  bf16x8 mh[2], ml[2];
#pragma unroll
  for (int qf = 0; qf < 2; ++qf) {
    const float* mp = mq + b * 1024 + (qf * 16 + col) * 32 + g * 8;
    const float4 ma = *reinterpret_cast<const float4*>(mp);
    const float4 mb = *reinterpret_cast<const float4*>(mp + 4);
    uint4 h, l;
    cvt2(ma.x, ma.y, h.x, l.x);
    cvt2(ma.z, ma.w, h.y, l.y);
    cvt2(mb.x, mb.y, h.z, l.z);
    cvt2(mb.z, mb.w, h.w, l.w);
    mh[qf] = __builtin_bit_cast(bf16x8, h);
    ml[qf] = __builtin_bit_cast(bf16x8, l);
  }

  // ---- stage 32 rows x 208 floats (52 slots/row, 1664 slots) ----
#pragma unroll
  for (int round = 0; round < 6; ++round) {
    const int v   = round * 256 + tid;        // slot = row*52 + c4
    const int row = v / 52;
    const int c4  = v - row * 52;
    gload16(xvb + row * Ss + off + c4 * 4,
            &lds[(round * 256 + w * 64) * 4]);
  }
  if (tid < 128) {                            // tail: slots 1536..1663 (waves 0,1)
    const int v   = 1536 + tid;
    const int row = v / 52;
    const int c4  = v - row * 52;
    gload16(xvb + row * Ss + off + c4 * 4, &lds[(1536 + w * 64) * 4]);
  }
  __syncthreads();                            // drains vmcnt: chunk staged

  // ---- compute: frag sf = w + 4*i; 12 frags (ch<3) or 13 (ch==3) ----
  const int nfrag = (ch == 3) ? 13 : 12;
  for (int sf = w; sf < nfrag; sf += 4) {
    float f8[8];
#pragma unroll
    for (int j = 0; j < 8; ++j)
      f8[j] = lds[(8 * g + j) * 208 + sf * 16 + col];
    uint4 hh, lv;
    cvt2(f8[0], f8[1], hh.x, lv.x);
    cvt2(f8[2], f8[3], hh.y, lv.y);
    cvt2(f8[4], f8[5], hh.z, lv.z);
    cvt2(f8[6], f8[7], hh.w, lv.w);
    const bf16x8 vh = __builtin_bit_cast(bf16x8, hh);
    const bf16x8 vl = __builtin_bit_cast(bf16x8, lv);
    const int s = off + sf * 16 + col;
#pragma unroll
    for (int qf = 0; qf < 2; ++qf) {
      f32x4 d = {0.f, 0.f, 0.f, 0.f};
      d = __builtin_amdgcn_mfma_f32_16x16x32_bf16(mh[qf], vl, d, 0, 0, 0);
      d = __builtin_amdgcn_mfma_f32_16x16x32_bf16(ml[qf], vh, d, 0, 0, 0);
      d = __builtin_amdgcn_mfma_f32_16x16x32_bf16(mh[qf], vh, d, 0, 0, 0);
#pragma unroll
      for (int r = 0; r < 4; ++r)
        ob[(size_t)(qf * 16 + g * 4 + r) * Ss + s] = d[r];   // m89 C/D map
    }
  }
}

}  // namespace

extern "C" void kernel_launch(void* const* d_in, const int* in_sizes, int n_in,
                              void* d_out, int out_size, void* d_ws, size_t ws_size,
                              hipStream_t stream) {
  const float* x  = (const float*)d_in[0];
  const float* xv = (const float*)d_in[1];
  float* out = (float*)d_out;

  // workspace (fp32), ~4.2 MiB total:
  float* part = (float*)d_ws;            // 1024 x 1024
  float* msum = part + 1024 * 1024;      // 16 x 1024
  float* mq   = msum + 16 * 1024;        // 16 x 1024 (q-major softmax weights)

  gram_partial<<<dim3(1024), dim3(256), 0, stream>>>(x, part);
  reduce_c<<<dim3(64), dim3(256), 0, stream>>>(part, msum);
  softmax_b<<<dim3(4), dim3(256), 0, stream>>>(msum, mq);
  pv<<<dim3(4096), dim3(256), 0, stream>>>(xv, mq, out);
}

// Round 17
// 77.540 us; speedup vs baseline: 1.4710x; 1.0039x over previous
//
#include <hip/hip_runtime.h>

namespace {

constexpr int Tt = 32;    // frames (t)
constexpr int Ss = 784;   // floats per row (h*w)

using bf16x8 = __attribute__((ext_vector_type(8))) short;
using f32x4  = __attribute__((ext_vector_type(4))) float;

// split fp32 -> hi (truncated bf16) + lo (bf16 of residual); pack 2 per uint
__device__ inline void cvt2(float a, float b, unsigned& h, unsigned& l) {
  const unsigned ha = __float_as_uint(a) >> 16;
  const unsigned hb = __float_as_uint(b) >> 16;
  const float ra = a - __uint_as_float(ha << 16);
  const float rb = b - __uint_as_float(hb << 16);
  const unsigned la = __float_as_uint(ra) >> 16;
  const unsigned lb = __float_as_uint(rb) >> 16;
  h = ha | (hb << 16);
  l = la | (lb << 16);
}

// async global->LDS, 16 B per lane; LDS dest must be wave-uniform base.
__device__ inline void gload16(const float* g, float* l) {
  __builtin_amdgcn_global_load_lds(
      (const __attribute__((address_space(1))) void*)g,
      (__attribute__((address_space(3))) void*)l, 16, 0, 0);
}

// ---------------------------------------------------------------------------
// Kernel 1: per-(b,c) Gram via split-bf16 MFMA, direct-global fragments
// (unchanged from rounds 10-16; measured ~16 us = its HBM floor).
// ---------------------------------------------------------------------------
__global__ __launch_bounds__(256, 4) void gram_partial(const float* __restrict__ x,
                                                       float* __restrict__ part) {
  const int bc = blockIdx.x;                       // b*64 + c
  const float* __restrict__ xb = x + (size_t)bc * (Tt * Ss);
  const int tid  = threadIdx.x;
  const int w    = tid >> 6;          // wave 0..3
  const int lane = tid & 63;
  const int col  = lane & 15;
  const int g    = lane >> 4;

  f32x4 d1[2][2], d2[2][2], d3[2][2];
#pragma unroll
  for (int i = 0; i < 2; ++i)
#pragma unroll
    for (int j = 0; j < 2; ++j) { d1[i][j] = 0.f; d2[i][j] = 0.f; d3[i][j] = 0.f; }

  const float* __restrict__ pa = xb + (size_t)col * Ss;         // rows 0-15
  const float* __restrict__ pb = xb + (size_t)(16 + col) * Ss;  // rows 16-31

  for (int ks = w; ks < 25; ks += 4) {
    const int s0 = ks * 32 + g * 8;
    uint4 ha = {0u,0u,0u,0u}, la = {0u,0u,0u,0u};
    uint4 hb = {0u,0u,0u,0u}, lb = {0u,0u,0u,0u};
    if (s0 < 784) {
      const float4 a0 = *reinterpret_cast<const float4*>(pa + s0);
      const float4 a1 = *reinterpret_cast<const float4*>(pa + s0 + 4);
      const float4 b0 = *reinterpret_cast<const float4*>(pb + s0);
      const float4 b1 = *reinterpret_cast<const float4*>(pb + s0 + 4);
      cvt2(a0.x, a0.y, ha.x, la.x);
      cvt2(a0.z, a0.w, ha.y, la.y);
      cvt2(a1.x, a1.y, ha.z, la.z);
      cvt2(a1.z, a1.w, ha.w, la.w);
      cvt2(b0.x, b0.y, hb.x, lb.x);
      cvt2(b0.z, b0.w, hb.y, lb.y);
      cvt2(b1.x, b1.y, hb.z, lb.z);
      cvt2(b1.z, b1.w, hb.w, lb.w);
    }
    const bf16x8 h0 = __builtin_bit_cast(bf16x8, ha);
    const bf16x8 l0 = __builtin_bit_cast(bf16x8, la);
    const bf16x8 h1 = __builtin_bit_cast(bf16x8, hb);
    const bf16x8 l1 = __builtin_bit_cast(bf16x8, lb);
    d1[0][0] = __builtin_amdgcn_mfma_f32_16x16x32_bf16(h0, h0, d1[0][0], 0, 0, 0);
    d1[0][1] = __builtin_amdgcn_mfma_f32_16x16x32_bf16(h0, h1, d1[0][1], 0, 0, 0);
    d1[1][0] = __builtin_amdgcn_mfma_f32_16x16x32_bf16(h1, h0, d1[1][0], 0, 0, 0);
    d1[1][1] = __builtin_amdgcn_mfma_f32_16x16x32_bf16(h1, h1, d1[1][1], 0, 0, 0);
    d2[0][0] = __builtin_amdgcn_mfma_f32_16x16x32_bf16(h0, l0, d2[0][0], 0, 0, 0);
    d2[0][1] = __builtin_amdgcn_mfma_f32_16x16x32_bf16(h0, l1, d2[0][1], 0, 0, 0);
    d2[1][0] = __builtin_amdgcn_mfma_f32_16x16x32_bf16(h1, l0, d2[1][0], 0, 0, 0);
    d2[1][1] = __builtin_amdgcn_mfma_f32_16x16x32_bf16(h1, l1, d2[1][1], 0, 0, 0);
    d3[0][0] = __builtin_amdgcn_mfma_f32_16x16x32_bf16(l0, h0, d3[0][0], 0, 0, 0);
    d3[0][1] = __builtin_amdgcn_mfma_f32_16x16x32_bf16(l0, h1, d3[0][1], 0, 0, 0);
    d3[1][0] = __builtin_amdgcn_mfma_f32_16x16x32_bf16(l1, h0, d3[1][0], 0, 0, 0);
    d3[1][1] = __builtin_amdgcn_mfma_f32_16x16x32_bf16(l1, h1, d3[1][1], 0, 0, 0);
  }

  // ---- epilogue: combine D1+D2+D3, reduce over 4 waves (LDS, 1 barrier) ----
  __shared__ float mtmp[4 * 1056];    // 16896 B
#pragma unroll
  for (int i = 0; i < 2; ++i)
#pragma unroll
    for (int j = 0; j < 2; ++j) {
      const f32x4 s4 = d1[i][j] + d2[i][j] + d3[i][j];
#pragma unroll
      for (int r = 0; r < 4; ++r) {
        const int row = i * 16 + g * 4 + r;       // m89-verified C/D map
        const int cc  = j * 16 + col;
        mtmp[w * 1056 + row * 33 + cc] = s4[r];
      }
    }
  __syncthreads();

  const int e0 = tid * 4;
  float tmp[4];
#pragma unroll
  for (int u = 0; u < 4; ++u) {
    const int row = (e0 + u) >> 5;
    const int cc  = (e0 + u) & 31;
    float ss = 0.f;
#pragma unroll
    for (int ww = 0; ww < 4; ++ww) ss += mtmp[ww * 1056 + row * 33 + cc];
    tmp[u] = ss;
  }
  float4 o4;
  o4.x = tmp[0]; o4.y = tmp[1]; o4.z = tmp[2]; o4.w = tmp[3];
  *reinterpret_cast<float4*>(part + (size_t)bc * 1024 + e0) = o4;
}

// ---------------------------------------------------------------------------
// Kernel 2: reduce partials over c.  msum[b][e] = sum_c part[b*64+c][e]
// ---------------------------------------------------------------------------
__global__ __launch_bounds__(256) void reduce_c(const float* __restrict__ part,
                                                float* __restrict__ msum) {
  const int bid = blockIdx.x;                // 0..63
  const int b   = bid >> 2;
  const int e   = (bid & 3) * 256 + threadIdx.x;   // 0..1023
  const float* __restrict__ p = part + (size_t)b * 64 * 1024 + e;
  float s0 = 0.f, s1 = 0.f, s2 = 0.f, s3 = 0.f;
#pragma unroll
  for (int c = 0; c < 64; c += 4) {
    s0 += p[(size_t)(c + 0) * 1024];
    s1 += p[(size_t)(c + 1) * 1024];
    s2 += p[(size_t)(c + 2) * 1024];
    s3 += p[(size_t)(c + 3) * 1024];
  }
  msum[b * 1024 + e] = (s0 + s1) + (s2 + s3);
}

// ---------------------------------------------------------------------------
// Kernel 3: softmax over the BATCH axis. Output q-major: mq[b][q*32+k].
// ---------------------------------------------------------------------------
__global__ __launch_bounds__(256) void softmax_b(const float* __restrict__ msum,
                                                 float* __restrict__ mq) {
  const int e = blockIdx.x * 256 + threadIdx.x;    // q*32 + k
  float l[16];
  float mx = -3.4e38f;
#pragma unroll
  for (int b = 0; b < 16; ++b) {
    l[b] = msum[b * 1024 + e];
    mx = fmaxf(mx, l[b]);
  }
  float s = 0.f;
#pragma unroll
  for (int b = 0; b < 16; ++b) {
    l[b] = expf(l[b] - mx);
    s += l[b];
  }
  const float inv = 1.f / s;
#pragma unroll
  for (int b = 0; b < 16; ++b) mq[b * 1024 + e] = l[b] * inv;
}

// ---------------------------------------------------------------------------
// Kernel 4: PV via split-bf16 MFMA — r16's validated math/staging with the
// occupancy limiter removed: chunk = 112 floats (784 = 7 x 112), LDS
// 32 x 112 fp32 = 14336 B -> LDS allows 8+ blocks/CU (r16's 26.6 KB fit only
// ~4 in the effective pool -> occupancy 47%). Grid 7168 = bc*7 + ch; every
// chunk = exactly 7 full 16-col frags (uniform, no masking, no tail).
// __launch_bounds__(256,8): VGPR cap 64, body measured 40 in r16 -> no spill.
// Per block: M-frags from q-major mq (L2-hot), one 14 KB zero-VGPR async
// stage, 1 barrier, then per frag: 8 ds_read_b32, cvt -> vh/vl, 6 MFMA
// (2 qf x {mh*vl, ml*vh, mh*vh}), 8 stores (m89 C/D map).
// ---------------------------------------------------------------------------
__global__ __launch_bounds__(256, 8) void pv(const float* __restrict__ xv,
                                             const float* __restrict__ mq,
                                             float* __restrict__ out) {
  const int gbl = blockIdx.x;                 // bc*7 + ch
  const int bc  = gbl / 7;
  const int ch  = gbl - bc * 7;
  const int b   = bc >> 6;
  const int off = ch * 112;                   // chunk start (floats)
  const float* __restrict__ xvb = xv + (size_t)bc * (Tt * Ss);
  float* __restrict__ ob        = out + (size_t)bc * (Tt * Ss);

  const int tid  = threadIdx.x;
  const int w    = tid >> 6;                  // wave 0..3
  const int lane = tid & 63;
  const int col  = lane & 15;                 // frag column / M row
  const int g    = lane >> 4;                 // k-group (k = 8g..8g+7)

  __shared__ float lds[32 * 112];             // 14336 B

  // ---- M fragments (once per block; mq is L2-hot) — r9/r16-validated ----
  bf16x8 mh[2], ml[2];
#pragma unroll
  for (int qf = 0; qf < 2; ++qf) {
    const float* mp = mq + b * 1024 + (qf * 16 + col) * 32 + g * 8;
    const float4 ma = *reinterpret_cast<const float4*>(mp);
    const float4 mb = *reinterpret_cast<const float4*>(mp + 4);
    uint4 h, l;
    cvt2(ma.x, ma.y, h.x, l.x);
    cvt2(ma.z, ma.w, h.y, l.y);
    cvt2(mb.x, mb.y, h.z, l.z);
    cvt2(mb.z, mb.w, h.w, l.w);
    mh[qf] = __builtin_bit_cast(bf16x8, h);
    ml[qf] = __builtin_bit_cast(bf16x8, l);
  }

  // ---- stage 32 rows x 112 floats (28 float4 slots/row, 896 slots) ----
#pragma unroll
  for (int round = 0; round < 3; ++round) {
    const int v   = round * 256 + tid;        // slot = row*28 + c4
    const int row = v / 28;
    const int c4  = v - row * 28;
    gload16(xvb + row * Ss + off + c4 * 4,
            &lds[(round * 256 + w * 64) * 4]);
  }
  if (tid < 128) {                            // tail: slots 768..895 (waves 0,1)
    const int v   = 768 + tid;
    const int row = v / 28;
    const int c4  = v - row * 28;
    gload16(xvb + row * Ss + off + c4 * 4, &lds[(768 + w * 64) * 4]);
  }
  __syncthreads();                            // drains vmcnt: chunk staged

  // ---- compute: 7 frags; wave w owns sf = w, w+4 ----
  for (int sf = w; sf < 7; sf += 4) {
    float f8[8];
#pragma unroll
    for (int j = 0; j < 8; ++j)
      f8[j] = lds[(8 * g + j) * 112 + sf * 16 + col];
    uint4 hh, lv;
    cvt2(f8[0], f8[1], hh.x, lv.x);
    cvt2(f8[2], f8[3], hh.y, lv.y);
    cvt2(f8[4], f8[5], hh.z, lv.z);
    cvt2(f8[6], f8[7], hh.w, lv.w);
    const bf16x8 vh = __builtin_bit_cast(bf16x8, hh);
    const bf16x8 vl = __builtin_bit_cast(bf16x8, lv);
    const int s = off + sf * 16 + col;
#pragma unroll
    for (int qf = 0; qf < 2; ++qf) {
      f32x4 d = {0.f, 0.f, 0.f, 0.f};
      d = __builtin_amdgcn_mfma_f32_16x16x32_bf16(mh[qf], vl, d, 0, 0, 0);
      d = __builtin_amdgcn_mfma_f32_16x16x32_bf16(ml[qf], vh, d, 0, 0, 0);
      d = __builtin_amdgcn_mfma_f32_16x16x32_bf16(mh[qf], vh, d, 0, 0, 0);
#pragma unroll
      for (int r = 0; r < 4; ++r)
        ob[(size_t)(qf * 16 + g * 4 + r) * Ss + s] = d[r];   // m89 C/D map
    }
  }
}

}  // namespace

extern "C" void kernel_launch(void* const* d_in, const int* in_sizes, int n_in,
                              void* d_out, int out_size, void* d_ws, size_t ws_size,
                              hipStream_t stream) {
  const float* x  = (const float*)d_in[0];
  const float* xv = (const float*)d_in[1];
  float* out = (float*)d_out;

  // workspace (fp32), ~4.2 MiB total:
  float* part = (float*)d_ws;            // 1024 x 1024
  float* msum = part + 1024 * 1024;      // 16 x 1024
  float* mq   = msum + 16 * 1024;        // 16 x 1024 (q-major softmax weights)

  gram_partial<<<dim3(1024), dim3(256), 0, stream>>>(x, part);
  reduce_c<<<dim3(64), dim3(256), 0, stream>>>(part, msum);
  softmax_b<<<dim3(4), dim3(256), 0, stream>>>(msum, mq);
  pv<<<dim3(7168), dim3(256), 0, stream>>>(xv, mq, out);
}

// Round 18
// 76.915 us; speedup vs baseline: 1.4830x; 1.0081x over previous
//
#include <hip/hip_runtime.h>

namespace {

constexpr int Tt = 32;    // frames (t)
constexpr int Ss = 784;   // floats per row (h*w)

using bf16x8 = __attribute__((ext_vector_type(8))) short;
using f32x4  = __attribute__((ext_vector_type(4))) float;

// split fp32 -> hi (truncated bf16) + lo (bf16 of residual); pack 2 per uint
__device__ inline void cvt2(float a, float b, unsigned& h, unsigned& l) {
  const unsigned ha = __float_as_uint(a) >> 16;
  const unsigned hb = __float_as_uint(b) >> 16;
  const float ra = a - __uint_as_float(ha << 16);
  const float rb = b - __uint_as_float(hb << 16);
  const unsigned la = __float_as_uint(ra) >> 16;
  const unsigned lb = __float_as_uint(rb) >> 16;
  h = ha | (hb << 16);
  l = la | (lb << 16);
}

// async global->LDS, 16 B per lane; LDS dest must be wave-uniform base.
__device__ inline void gload16(const float* g, float* l) {
  __builtin_amdgcn_global_load_lds(
      (const __attribute__((address_space(1))) void*)g,
      (__attribute__((address_space(3))) void*)l, 16, 0, 0);
}

// ---------------------------------------------------------------------------
// Kernel 1: per-(b,c) Gram via split-bf16 MFMA, direct-global fragments
// (unchanged from rounds 10-17; measured ~16 us = its HBM floor).
// ---------------------------------------------------------------------------
__global__ __launch_bounds__(256, 4) void gram_partial(const float* __restrict__ x,
                                                       float* __restrict__ part) {
  const int bc = blockIdx.x;                       // b*64 + c
  const float* __restrict__ xb = x + (size_t)bc * (Tt * Ss);
  const int tid  = threadIdx.x;
  const int w    = tid >> 6;          // wave 0..3
  const int lane = tid & 63;
  const int col  = lane & 15;
  const int g    = lane >> 4;

  f32x4 d1[2][2], d2[2][2], d3[2][2];
#pragma unroll
  for (int i = 0; i < 2; ++i)
#pragma unroll
    for (int j = 0; j < 2; ++j) { d1[i][j] = 0.f; d2[i][j] = 0.f; d3[i][j] = 0.f; }

  const float* __restrict__ pa = xb + (size_t)col * Ss;         // rows 0-15
  const float* __restrict__ pb = xb + (size_t)(16 + col) * Ss;  // rows 16-31

  for (int ks = w; ks < 25; ks += 4) {
    const int s0 = ks * 32 + g * 8;
    uint4 ha = {0u,0u,0u,0u}, la = {0u,0u,0u,0u};
    uint4 hb = {0u,0u,0u,0u}, lb = {0u,0u,0u,0u};
    if (s0 < 784) {
      const float4 a0 = *reinterpret_cast<const float4*>(pa + s0);
      const float4 a1 = *reinterpret_cast<const float4*>(pa + s0 + 4);
      const float4 b0 = *reinterpret_cast<const float4*>(pb + s0);
      const float4 b1 = *reinterpret_cast<const float4*>(pb + s0 + 4);
      cvt2(a0.x, a0.y, ha.x, la.x);
      cvt2(a0.z, a0.w, ha.y, la.y);
      cvt2(a1.x, a1.y, ha.z, la.z);
      cvt2(a1.z, a1.w, ha.w, la.w);
      cvt2(b0.x, b0.y, hb.x, lb.x);
      cvt2(b0.z, b0.w, hb.y, lb.y);
      cvt2(b1.x, b1.y, hb.z, lb.z);
      cvt2(b1.z, b1.w, hb.w, lb.w);
    }
    const bf16x8 h0 = __builtin_bit_cast(bf16x8, ha);
    const bf16x8 l0 = __builtin_bit_cast(bf16x8, la);
    const bf16x8 h1 = __builtin_bit_cast(bf16x8, hb);
    const bf16x8 l1 = __builtin_bit_cast(bf16x8, lb);
    d1[0][0] = __builtin_amdgcn_mfma_f32_16x16x32_bf16(h0, h0, d1[0][0], 0, 0, 0);
    d1[0][1] = __builtin_amdgcn_mfma_f32_16x16x32_bf16(h0, h1, d1[0][1], 0, 0, 0);
    d1[1][0] = __builtin_amdgcn_mfma_f32_16x16x32_bf16(h1, h0, d1[1][0], 0, 0, 0);
    d1[1][1] = __builtin_amdgcn_mfma_f32_16x16x32_bf16(h1, h1, d1[1][1], 0, 0, 0);
    d2[0][0] = __builtin_amdgcn_mfma_f32_16x16x32_bf16(h0, l0, d2[0][0], 0, 0, 0);
    d2[0][1] = __builtin_amdgcn_mfma_f32_16x16x32_bf16(h0, l1, d2[0][1], 0, 0, 0);
    d2[1][0] = __builtin_amdgcn_mfma_f32_16x16x32_bf16(h1, l0, d2[1][0], 0, 0, 0);
    d2[1][1] = __builtin_amdgcn_mfma_f32_16x16x32_bf16(h1, l1, d2[1][1], 0, 0, 0);
    d3[0][0] = __builtin_amdgcn_mfma_f32_16x16x32_bf16(l0, h0, d3[0][0], 0, 0, 0);
    d3[0][1] = __builtin_amdgcn_mfma_f32_16x16x32_bf16(l0, h1, d3[0][1], 0, 0, 0);
    d3[1][0] = __builtin_amdgcn_mfma_f32_16x16x32_bf16(l1, h0, d3[1][0], 0, 0, 0);
    d3[1][1] = __builtin_amdgcn_mfma_f32_16x16x32_bf16(l1, h1, d3[1][1], 0, 0, 0);
  }

  // ---- epilogue: combine D1+D2+D3, reduce over 4 waves (LDS, 1 barrier) ----
  __shared__ float mtmp[4 * 1056];    // 16896 B
#pragma unroll
  for (int i = 0; i < 2; ++i)
#pragma unroll
    for (int j = 0; j < 2; ++j) {
      const f32x4 s4 = d1[i][j] + d2[i][j] + d3[i][j];
#pragma unroll
      for (int r = 0; r < 4; ++r) {
        const int row = i * 16 + g * 4 + r;       // m89-verified C/D map
        const int cc  = j * 16 + col;
        mtmp[w * 1056 + row * 33 + cc] = s4[r];
      }
    }
  __syncthreads();

  const int e0 = tid * 4;
  float tmp[4];
#pragma unroll
  for (int u = 0; u < 4; ++u) {
    const int row = (e0 + u) >> 5;
    const int cc  = (e0 + u) & 31;
    float ss = 0.f;
#pragma unroll
    for (int ww = 0; ww < 4; ++ww) ss += mtmp[ww * 1056 + row * 33 + cc];
    tmp[u] = ss;
  }
  float4 o4;
  o4.x = tmp[0]; o4.y = tmp[1]; o4.z = tmp[2]; o4.w = tmp[3];
  *reinterpret_cast<float4*>(part + (size_t)bc * 1024 + e0) = o4;
}

// ---------------------------------------------------------------------------
// Kernel 2: reduce partials over c.  msum[b][e] = sum_c part[b*64+c][e]
// ---------------------------------------------------------------------------
__global__ __launch_bounds__(256) void reduce_c(const float* __restrict__ part,
                                                float* __restrict__ msum) {
  const int bid = blockIdx.x;                // 0..63
  const int b   = bid >> 2;
  const int e   = (bid & 3) * 256 + threadIdx.x;   // 0..1023
  const float* __restrict__ p = part + (size_t)b * 64 * 1024 + e;
  float s0 = 0.f, s1 = 0.f, s2 = 0.f, s3 = 0.f;
#pragma unroll
  for (int c = 0; c < 64; c += 4) {
    s0 += p[(size_t)(c + 0) * 1024];
    s1 += p[(size_t)(c + 1) * 1024];
    s2 += p[(size_t)(c + 2) * 1024];
    s3 += p[(size_t)(c + 3) * 1024];
  }
  msum[b * 1024 + e] = (s0 + s1) + (s2 + s3);
}

// ---------------------------------------------------------------------------
// Kernel 3: softmax over the BATCH axis. Output q-major: mq[b][q*32+k].
// ---------------------------------------------------------------------------
__global__ __launch_bounds__(256) void softmax_b(const float* __restrict__ msum,
                                                 float* __restrict__ mq) {
  const int e = blockIdx.x * 256 + threadIdx.x;    // q*32 + k
  float l[16];
  float mx = -3.4e38f;
#pragma unroll
  for (int b = 0; b < 16; ++b) {
    l[b] = msum[b * 1024 + e];
    mx = fmaxf(mx, l[b]);
  }
  float s = 0.f;
#pragma unroll
  for (int b = 0; b < 16; ++b) {
    l[b] = expf(l[b] - mx);
    s += l[b];
  }
  const float inv = 1.f / s;
#pragma unroll
  for (int b = 0; b < 16; ++b) mq[b * 1024 + e] = l[b] * inv;
}

// ---------------------------------------------------------------------------
// Kernel 4: PV via split-bf16 MFMA — r16's validated staging, OPERAND-SWAPPED
// MFMA for float4 stores.
// mfma(A,B) = A·B^T with D[row from A][col from B] (gram-validated). Swapping
// to d = mfma(vh, mh[qf]) gives D[s_local][q_local]; C/D map row = 4g+r =>
// each lane's 4 regs are 4 CONSECUTIVE s -> ONE float4 store per qf (was 4
// scalar dwords). Same fragment registers, same loads, same math.
// Waves own consecutive frag TRIPLES (sf = 3w..3w+2; wave 3 takes the ch==3
// 13th frag) so both 64B halves of most 128B output lines are written by the
// same wave back-to-back -> L2 write-combining.
// Grid 4096 = bc*4 + ch; chunk offsets {0,192,384,576} floats (line-aligned;
// r17's 448B chunks were not). Stage 208 floats/row (uniform, r16-validated).
// LDS 26624 B; __launch_bounds__(256,4) (VGPR cap 128, no spill).
// ---------------------------------------------------------------------------
__global__ __launch_bounds__(256, 4) void pv(const float* __restrict__ xv,
                                             const float* __restrict__ mq,
                                             float* __restrict__ out) {
  const int gbl = blockIdx.x;                 // bc*4 + ch
  const int bc  = gbl >> 2;
  const int ch  = gbl & 3;
  const int b   = bc >> 6;
  const int off = ch * 192;                   // chunk start (floats)
  const float* __restrict__ xvb = xv + (size_t)bc * (Tt * Ss);
  float* __restrict__ ob        = out + (size_t)bc * (Tt * Ss);

  const int tid  = threadIdx.x;
  const int w    = tid >> 6;                  // wave 0..3
  const int lane = tid & 63;
  const int col  = lane & 15;                 // frag column / M row
  const int g    = lane >> 4;                 // k-group (k = 8g..8g+7)

  __shared__ float lds[32 * 208];             // 26624 B

  // ---- M fragments (once per block; mq is L2-hot) — r9/r16-validated ----
  bf16x8 mh[2], ml[2];
#pragma unroll
  for (int qf = 0; qf < 2; ++qf) {
    const float* mp = mq + b * 1024 + (qf * 16 + col) * 32 + g * 8;
    const float4 ma = *reinterpret_cast<const float4*>(mp);
    const float4 mb = *reinterpret_cast<const float4*>(mp + 4);
    uint4 h, l;
    cvt2(ma.x, ma.y, h.x, l.x);
    cvt2(ma.z, ma.w, h.y, l.y);
    cvt2(mb.x, mb.y, h.z, l.z);
    cvt2(mb.z, mb.w, h.w, l.w);
    mh[qf] = __builtin_bit_cast(bf16x8, h);
    ml[qf] = __builtin_bit_cast(bf16x8, l);
  }

  // ---- stage 32 rows x 208 floats (52 slots/row, 1664 slots) ----
#pragma unroll
  for (int round = 0; round < 6; ++round) {
    const int v   = round * 256 + tid;        // slot = row*52 + c4
    const int row = v / 52;
    const int c4  = v - row * 52;
    gload16(xvb + row * Ss + off + c4 * 4,
            &lds[(round * 256 + w * 64) * 4]);
  }
  if (tid < 128) {                            // tail: slots 1536..1663 (waves 0,1)
    const int v   = 1536 + tid;
    const int row = v / 52;
    const int c4  = v - row * 52;
    gload16(xvb + row * Ss + off + c4 * 4, &lds[(1536 + w * 64) * 4]);
  }
  __syncthreads();                            // drains vmcnt: chunk staged

  // ---- compute: frag triples per wave; sf = 3w .. 3w+2 (+frag 12 on w=3) ----
  const int nfrag = (ch == 3) ? 13 : 12;
  const int fend  = (w == 3) ? nfrag : 3 * w + 3;
  for (int sf = 3 * w; sf < fend; ++sf) {
    float f8[8];
#pragma unroll
    for (int j = 0; j < 8; ++j)
      f8[j] = lds[(8 * g + j) * 208 + sf * 16 + col];
    uint4 hh, lv;
    cvt2(f8[0], f8[1], hh.x, lv.x);
    cvt2(f8[2], f8[3], hh.y, lv.y);
    cvt2(f8[4], f8[5], hh.z, lv.z);
    cvt2(f8[6], f8[7], hh.w, lv.w);
    const bf16x8 vh = __builtin_bit_cast(bf16x8, hh);
    const bf16x8 vl = __builtin_bit_cast(bf16x8, lv);
    const int s0 = off + sf * 16;
#pragma unroll
    for (int qf = 0; qf < 2; ++qf) {
      f32x4 d = {0.f, 0.f, 0.f, 0.f};
      d = __builtin_amdgcn_mfma_f32_16x16x32_bf16(vl, mh[qf], d, 0, 0, 0);
      d = __builtin_amdgcn_mfma_f32_16x16x32_bf16(vh, ml[qf], d, 0, 0, 0);
      d = __builtin_amdgcn_mfma_f32_16x16x32_bf16(vh, mh[qf], d, 0, 0, 0);
      // D[s_local][q_local]: lane(col,g) regs = s = s0+4g..+3, q = qf*16+col
      float4 o4;
      o4.x = d[0]; o4.y = d[1]; o4.z = d[2]; o4.w = d[3];
      *reinterpret_cast<float4*>(ob + (size_t)(qf * 16 + col) * Ss + s0 + 4 * g) = o4;
    }
  }
}

}  // namespace

extern "C" void kernel_launch(void* const* d_in, const int* in_sizes, int n_in,
                              void* d_out, int out_size, void* d_ws, size_t ws_size,
                              hipStream_t stream) {
  const float* x  = (const float*)d_in[0];
  const float* xv = (const float*)d_in[1];
  float* out = (float*)d_out;

  // workspace (fp32), ~4.2 MiB total:
  float* part = (float*)d_ws;            // 1024 x 1024
  float* msum = part + 1024 * 1024;      // 16 x 1024
  float* mq   = msum + 16 * 1024;        // 16 x 1024 (q-major softmax weights)

  gram_partial<<<dim3(1024), dim3(256), 0, stream>>>(x, part);
  reduce_c<<<dim3(64), dim3(256), 0, stream>>>(part, msum);
  softmax_b<<<dim3(4), dim3(256), 0, stream>>>(msum, mq);
  pv<<<dim3(4096), dim3(256), 0, stream>>>(xv, mq, out);
}

// Round 19
// 73.228 us; speedup vs baseline: 1.5576x; 1.0503x over previous
//
#include <hip/hip_runtime.h>

namespace {

constexpr int Tt = 32;    // frames (t)
constexpr int Ss = 784;   // floats per row (h*w)

using bf16x8 = __attribute__((ext_vector_type(8))) short;
using f32x4  = __attribute__((ext_vector_type(4))) float;

// split fp32 -> hi (truncated bf16) + lo (bf16 of residual); pack 2 per uint
__device__ inline void cvt2(float a, float b, unsigned& h, unsigned& l) {
  const unsigned ha = __float_as_uint(a) >> 16;
  const unsigned hb = __float_as_uint(b) >> 16;
  const float ra = a - __uint_as_float(ha << 16);
  const float rb = b - __uint_as_float(hb << 16);
  const unsigned la = __float_as_uint(ra) >> 16;
  const unsigned lb = __float_as_uint(rb) >> 16;
  h = ha | (hb << 16);
  l = la | (lb << 16);
}

// async global->LDS, 16 B per lane; LDS dest must be wave-uniform base.
__device__ inline void gload16(const float* g, float* l) {
  __builtin_amdgcn_global_load_lds(
      (const __attribute__((address_space(1))) void*)g,
      (__attribute__((address_space(3))) void*)l, 16, 0, 0);
}

// ---------------------------------------------------------------------------
// Kernel 1: per-(b,c) Gram via split-bf16 MFMA, direct-global fragments
// (unchanged from rounds 10-18; measured ~16 us = its HBM floor).
// ---------------------------------------------------------------------------
__global__ __launch_bounds__(256, 4) void gram_partial(const float* __restrict__ x,
                                                       float* __restrict__ part) {
  const int bc = blockIdx.x;                       // b*64 + c
  const float* __restrict__ xb = x + (size_t)bc * (Tt * Ss);
  const int tid  = threadIdx.x;
  const int w    = tid >> 6;          // wave 0..3
  const int lane = tid & 63;
  const int col  = lane & 15;
  const int g    = lane >> 4;

  f32x4 d1[2][2], d2[2][2], d3[2][2];
#pragma unroll
  for (int i = 0; i < 2; ++i)
#pragma unroll
    for (int j = 0; j < 2; ++j) { d1[i][j] = 0.f; d2[i][j] = 0.f; d3[i][j] = 0.f; }

  const float* __restrict__ pa = xb + (size_t)col * Ss;         // rows 0-15
  const float* __restrict__ pb = xb + (size_t)(16 + col) * Ss;  // rows 16-31

  for (int ks = w; ks < 25; ks += 4) {
    const int s0 = ks * 32 + g * 8;
    uint4 ha = {0u,0u,0u,0u}, la = {0u,0u,0u,0u};
    uint4 hb = {0u,0u,0u,0u}, lb = {0u,0u,0u,0u};
    if (s0 < 784) {
      const float4 a0 = *reinterpret_cast<const float4*>(pa + s0);
      const float4 a1 = *reinterpret_cast<const float4*>(pa + s0 + 4);
      const float4 b0 = *reinterpret_cast<const float4*>(pb + s0);
      const float4 b1 = *reinterpret_cast<const float4*>(pb + s0 + 4);
      cvt2(a0.x, a0.y, ha.x, la.x);
      cvt2(a0.z, a0.w, ha.y, la.y);
      cvt2(a1.x, a1.y, ha.z, la.z);
      cvt2(a1.z, a1.w, ha.w, la.w);
      cvt2(b0.x, b0.y, hb.x, lb.x);
      cvt2(b0.z, b0.w, hb.y, lb.y);
      cvt2(b1.x, b1.y, hb.z, lb.z);
      cvt2(b1.z, b1.w, hb.w, lb.w);
    }
    const bf16x8 h0 = __builtin_bit_cast(bf16x8, ha);
    const bf16x8 l0 = __builtin_bit_cast(bf16x8, la);
    const bf16x8 h1 = __builtin_bit_cast(bf16x8, hb);
    const bf16x8 l1 = __builtin_bit_cast(bf16x8, lb);
    d1[0][0] = __builtin_amdgcn_mfma_f32_16x16x32_bf16(h0, h0, d1[0][0], 0, 0, 0);
    d1[0][1] = __builtin_amdgcn_mfma_f32_16x16x32_bf16(h0, h1, d1[0][1], 0, 0, 0);
    d1[1][0] = __builtin_amdgcn_mfma_f32_16x16x32_bf16(h1, h0, d1[1][0], 0, 0, 0);
    d1[1][1] = __builtin_amdgcn_mfma_f32_16x16x32_bf16(h1, h1, d1[1][1], 0, 0, 0);
    d2[0][0] = __builtin_amdgcn_mfma_f32_16x16x32_bf16(h0, l0, d2[0][0], 0, 0, 0);
    d2[0][1] = __builtin_amdgcn_mfma_f32_16x16x32_bf16(h0, l1, d2[0][1], 0, 0, 0);
    d2[1][0] = __builtin_amdgcn_mfma_f32_16x16x32_bf16(h1, l0, d2[1][0], 0, 0, 0);
    d2[1][1] = __builtin_amdgcn_mfma_f32_16x16x32_bf16(h1, l1, d2[1][1], 0, 0, 0);
    d3[0][0] = __builtin_amdgcn_mfma_f32_16x16x32_bf16(l0, h0, d3[0][0], 0, 0, 0);
    d3[0][1] = __builtin_amdgcn_mfma_f32_16x16x32_bf16(l0, h1, d3[0][1], 0, 0, 0);
    d3[1][0] = __builtin_amdgcn_mfma_f32_16x16x32_bf16(l1, h0, d3[1][0], 0, 0, 0);
    d3[1][1] = __builtin_amdgcn_mfma_f32_16x16x32_bf16(l1, h1, d3[1][1], 0, 0, 0);
  }

  // ---- epilogue: combine D1+D2+D3, reduce over 4 waves (LDS, 1 barrier) ----
  __shared__ float mtmp[4 * 1056];    // 16896 B
#pragma unroll
  for (int i = 0; i < 2; ++i)
#pragma unroll
    for (int j = 0; j < 2; ++j) {
      const f32x4 s4 = d1[i][j] + d2[i][j] + d3[i][j];
#pragma unroll
      for (int r = 0; r < 4; ++r) {
        const int row = i * 16 + g * 4 + r;       // m89-verified C/D map
        const int cc  = j * 16 + col;
        mtmp[w * 1056 + row * 33 + cc] = s4[r];
      }
    }
  __syncthreads();

  const int e0 = tid * 4;
  float tmp[4];
#pragma unroll
  for (int u = 0; u < 4; ++u) {
    const int row = (e0 + u) >> 5;
    const int cc  = (e0 + u) & 31;
    float ss = 0.f;
#pragma unroll
    for (int ww = 0; ww < 4; ++ww) ss += mtmp[ww * 1056 + row * 33 + cc];
    tmp[u] = ss;
  }
  float4 o4;
  o4.x = tmp[0]; o4.y = tmp[1]; o4.z = tmp[2]; o4.w = tmp[3];
  *reinterpret_cast<float4*>(part + (size_t)bc * 1024 + e0) = o4;
}

// ---------------------------------------------------------------------------
// Kernel 2: reduce partials over c.  msum[b][e] = sum_c part[b*64+c][e]
// ---------------------------------------------------------------------------
__global__ __launch_bounds__(256) void reduce_c(const float* __restrict__ part,
                                                float* __restrict__ msum) {
  const int bid = blockIdx.x;                // 0..63
  const int b   = bid >> 2;
  const int e   = (bid & 3) * 256 + threadIdx.x;   // 0..1023
  const float* __restrict__ p = part + (size_t)b * 64 * 1024 + e;
  float s0 = 0.f, s1 = 0.f, s2 = 0.f, s3 = 0.f;
#pragma unroll
  for (int c = 0; c < 64; c += 4) {
    s0 += p[(size_t)(c + 0) * 1024];
    s1 += p[(size_t)(c + 1) * 1024];
    s2 += p[(size_t)(c + 2) * 1024];
    s3 += p[(size_t)(c + 3) * 1024];
  }
  msum[b * 1024 + e] = (s0 + s1) + (s2 + s3);
}

// ---------------------------------------------------------------------------
// Kernel 3: softmax over the BATCH axis. Output q-major: mq[b][q*32+k].
// ---------------------------------------------------------------------------
__global__ __launch_bounds__(256) void softmax_b(const float* __restrict__ msum,
                                                 float* __restrict__ mq) {
  const int e = blockIdx.x * 256 + threadIdx.x;    // q*32 + k
  float l[16];
  float mx = -3.4e38f;
#pragma unroll
  for (int b = 0; b < 16; ++b) {
    l[b] = msum[b * 1024 + e];
    mx = fmaxf(mx, l[b]);
  }
  float s = 0.f;
#pragma unroll
  for (int b = 0; b < 16; ++b) {
    l[b] = expf(l[b] - mx);
    s += l[b];
  }
  const float inv = 1.f / s;
#pragma unroll
  for (int b = 0; b < 16; ++b) mq[b * 1024 + e] = l[b] * inv;
}

// ---------------------------------------------------------------------------
// Kernel 4: PV via split-bf16 MFMA + T4 COUNTED-VMCNT double-buffer.
// Theory: all prior pv variants (57-62 us) convoy read/write phases around a
// full vmcnt(0) drain at __syncthreads -> read stream ~1 TB/s, write ~1.7.
// Fix: raw s_barrier + inline-asm counted s_waitcnt vmcnt(N) so the NEXT
// chunk's loads stay in flight across compute/stores (guide T3/T4; m218).
// 1024 blocks (one bc; 4/CU fully resident) x 256 thr; 2 x 16 KB buffers.
// 784 = 6 chunks x 128 floats (8 frags, 2/wave: sf=2w,2w+1) + 16-float tail
// (direct-global, wave 3). Per chunk: vmcnt(N) -> s_barrier -> [8 ds_read,
// cvt, 6 swapped-MFMA, 2 float4 stores] x2 -> lgkmcnt(0) -> s_barrier ->
// stage(ch+2). vmcnt counts loads AND stores (in-order): steady N=8
// (4 stores(ch-1) + 4 loads(ch+1)); edges N=4. NO __syncthreads anywhere.
// Compute/math byte-identical to r18 (validated, absmax 0.0625).
// ---------------------------------------------------------------------------
__global__ __launch_bounds__(256, 4) void pv(const float* __restrict__ xv,
                                             const float* __restrict__ mq,
                                             float* __restrict__ out) {
  const int bc = blockIdx.x;                  // b*64 + c
  const int b  = bc >> 6;
  const float* __restrict__ xvb = xv + (size_t)bc * (Tt * Ss);
  float* __restrict__ ob        = out + (size_t)bc * (Tt * Ss);

  const int tid  = threadIdx.x;
  const int w    = tid >> 6;                  // wave 0..3
  const int lane = tid & 63;
  const int col  = lane & 15;                 // frag column / M row
  const int g    = lane >> 4;                 // k-group (k = 8g..8g+7)

  __shared__ float lds[2][32 * 128];          // 2 x 16384 B

  // ---- M fragments (once per block; compiler waits for mv before cvt2) ----
  bf16x8 mh[2], ml[2];
#pragma unroll
  for (int qf = 0; qf < 2; ++qf) {
    const float* mp = mq + b * 1024 + (qf * 16 + col) * 32 + g * 8;
    const float4 ma = *reinterpret_cast<const float4*>(mp);
    const float4 mb = *reinterpret_cast<const float4*>(mp + 4);
    uint4 h, l;
    cvt2(ma.x, ma.y, h.x, l.x);
    cvt2(ma.z, ma.w, h.y, l.y);
    cvt2(mb.x, mb.y, h.z, l.z);
    cvt2(mb.z, mb.w, h.w, l.w);
    mh[qf] = __builtin_bit_cast(bf16x8, h);
    ml[qf] = __builtin_bit_cast(bf16x8, l);
  }

  // stage chunk ch (128 floats at off = ch*128) into buffer buf:
  // 1024 slots = 4 rounds x 256; slot v = row*32 + c4; LDS linear (slot = v).
  // 4 gload16 wave-instructions per wave per chunk.
  auto stage = [&](int buf, int ch) {
    const int off = ch * 128;
#pragma unroll
    for (int round = 0; round < 4; ++round) {
      const int v   = round * 256 + tid;
      const int row = v >> 5;
      const int c4  = v & 31;
      gload16(xvb + row * Ss + off + c4 * 4,
              &lds[buf][(round * 256 + w * 64) * 4]);
    }
  };

  stage(0, 0);
  stage(1, 1);

#pragma unroll
  for (int ch = 0; ch < 6; ++ch) {
    // counted wait: chunk ch's loads done; newer loads/stores stay in flight.
    if (ch == 0 || ch == 5) {
      asm volatile("s_waitcnt vmcnt(4)" ::: "memory");
    } else {
      asm volatile("s_waitcnt vmcnt(8)" ::: "memory");
    }
    __builtin_amdgcn_sched_barrier(0);
    __builtin_amdgcn_s_barrier();               // all waves' ch-loads landed

    const float* __restrict__ lbuf = lds[ch & 1];
    const int off = ch * 128;
#pragma unroll
    for (int fi = 0; fi < 2; ++fi) {
      const int sf = 2 * w + fi;                // this wave's frag
      float f8[8];
#pragma unroll
      for (int j = 0; j < 8; ++j)
        f8[j] = lbuf[(8 * g + j) * 128 + sf * 16 + col];
      uint4 hh, lv;
      cvt2(f8[0], f8[1], hh.x, lv.x);
      cvt2(f8[2], f8[3], hh.y, lv.y);
      cvt2(f8[4], f8[5], hh.z, lv.z);
      cvt2(f8[6], f8[7], hh.w, lv.w);
      const bf16x8 vh = __builtin_bit_cast(bf16x8, hh);
      const bf16x8 vl = __builtin_bit_cast(bf16x8, lv);
      const int s0 = off + sf * 16;
#pragma unroll
      for (int qf = 0; qf < 2; ++qf) {
        f32x4 d = {0.f, 0.f, 0.f, 0.f};
        d = __builtin_amdgcn_mfma_f32_16x16x32_bf16(vl, mh[qf], d, 0, 0, 0);
        d = __builtin_amdgcn_mfma_f32_16x16x32_bf16(vh, ml[qf], d, 0, 0, 0);
        d = __builtin_amdgcn_mfma_f32_16x16x32_bf16(vh, mh[qf], d, 0, 0, 0);
        // D[s][q]: lane(col,g) regs = s0+4g..+3 of q-row qf*16+col (r18-valid)
        float4 o4;
        o4.x = d[0]; o4.y = d[1]; o4.z = d[2]; o4.w = d[3];
        *reinterpret_cast<float4*>(ob + (size_t)(qf * 16 + col) * Ss + s0 + 4 * g) = o4;
      }
    }
    asm volatile("s_waitcnt lgkmcnt(0)" ::: "memory");   // LDS reads done
    __builtin_amdgcn_sched_barrier(0);
    __builtin_amdgcn_s_barrier();               // buffer free to restage
    if (ch < 4) stage(ch & 1, ch + 2);          // keep next loads in flight
  }

  // ---- tail frag: s = 768..783, direct from global (wave 3 only) ----
  if (w == 3) {
    float f8[8];
#pragma unroll
    for (int j = 0; j < 8; ++j)
      f8[j] = xvb[(size_t)(8 * g + j) * Ss + 768 + col];
    uint4 hh, lv;
    cvt2(f8[0], f8[1], hh.x, lv.x);
    cvt2(f8[2], f8[3], hh.y, lv.y);
    cvt2(f8[4], f8[5], hh.z, lv.z);
    cvt2(f8[6], f8[7], hh.w, lv.w);
    const bf16x8 vh = __builtin_bit_cast(bf16x8, hh);
    const bf16x8 vl = __builtin_bit_cast(bf16x8, lv);
#pragma unroll
    for (int qf = 0; qf < 2; ++qf) {
      f32x4 d = {0.f, 0.f, 0.f, 0.f};
      d = __builtin_amdgcn_mfma_f32_16x16x32_bf16(vl, mh[qf], d, 0, 0, 0);
      d = __builtin_amdgcn_mfma_f32_16x16x32_bf16(vh, ml[qf], d, 0, 0, 0);
      d = __builtin_amdgcn_mfma_f32_16x16x32_bf16(vh, mh[qf], d, 0, 0, 0);
      float4 o4;
      o4.x = d[0]; o4.y = d[1]; o4.z = d[2]; o4.w = d[3];
      *reinterpret_cast<float4*>(ob + (size_t)(qf * 16 + col) * Ss + 768 + 4 * g) = o4;
    }
  }
}

}  // namespace

extern "C" void kernel_launch(void* const* d_in, const int* in_sizes, int n_in,
                              void* d_out, int out_size, void* d_ws, size_t ws_size,
                              hipStream_t stream) {
  const float* x  = (const float*)d_in[0];
  const float* xv = (const float*)d_in[1];
  float* out = (float*)d_out;

  // workspace (fp32), ~4.2 MiB total:
  float* part = (float*)d_ws;            // 1024 x 1024
  float* msum = part + 1024 * 1024;      // 16 x 1024
  float* mq   = msum + 16 * 1024;        // 16 x 1024 (q-major softmax weights)

  gram_partial<<<dim3(1024), dim3(256), 0, stream>>>(x, part);
  reduce_c<<<dim3(64), dim3(256), 0, stream>>>(part, msum);
  softmax_b<<<dim3(4), dim3(256), 0, stream>>>(msum, mq);
  pv<<<dim3(1024), dim3(256), 0, stream>>>(xv, mq, out);
}

// Round 20
// 73.183 us; speedup vs baseline: 1.5586x; 1.0006x over previous
//
#include <hip/hip_runtime.h>

namespace {

constexpr int Tt = 32;    // frames (t)
constexpr int Ss = 784;   // floats per row (h*w)

using bf16x8 = __attribute__((ext_vector_type(8))) short;
using f32x4  = __attribute__((ext_vector_type(4))) float;

// split fp32 -> hi (truncated bf16) + lo (bf16 of residual); pack 2 per uint
__device__ inline void cvt2(float a, float b, unsigned& h, unsigned& l) {
  const unsigned ha = __float_as_uint(a) >> 16;
  const unsigned hb = __float_as_uint(b) >> 16;
  const float ra = a - __uint_as_float(ha << 16);
  const float rb = b - __uint_as_float(hb << 16);
  const unsigned la = __float_as_uint(ra) >> 16;
  const unsigned lb = __float_as_uint(rb) >> 16;
  h = ha | (hb << 16);
  l = la | (lb << 16);
}

// async global->LDS, 16 B per lane; LDS dest must be wave-uniform base.
__device__ inline void gload16(const float* g, float* l) {
  __builtin_amdgcn_global_load_lds(
      (const __attribute__((address_space(1))) void*)g,
      (__attribute__((address_space(3))) void*)l, 16, 0, 0);
}

// ---------------------------------------------------------------------------
// Kernel 1: per-(b,c) Gram via split-bf16 MFMA, direct-global fragments
// (unchanged from rounds 10-19; measured ~15 us = its HBM floor).
// ---------------------------------------------------------------------------
__global__ __launch_bounds__(256, 4) void gram_partial(const float* __restrict__ x,
                                                       float* __restrict__ part) {
  const int bc = blockIdx.x;                       // b*64 + c
  const float* __restrict__ xb = x + (size_t)bc * (Tt * Ss);
  const int tid  = threadIdx.x;
  const int w    = tid >> 6;          // wave 0..3
  const int lane = tid & 63;
  const int col  = lane & 15;
  const int g    = lane >> 4;

  f32x4 d1[2][2], d2[2][2], d3[2][2];
#pragma unroll
  for (int i = 0; i < 2; ++i)
#pragma unroll
    for (int j = 0; j < 2; ++j) { d1[i][j] = 0.f; d2[i][j] = 0.f; d3[i][j] = 0.f; }

  const float* __restrict__ pa = xb + (size_t)col * Ss;         // rows 0-15
  const float* __restrict__ pb = xb + (size_t)(16 + col) * Ss;  // rows 16-31

  for (int ks = w; ks < 25; ks += 4) {
    const int s0 = ks * 32 + g * 8;
    uint4 ha = {0u,0u,0u,0u}, la = {0u,0u,0u,0u};
    uint4 hb = {0u,0u,0u,0u}, lb = {0u,0u,0u,0u};
    if (s0 < 784) {
      const float4 a0 = *reinterpret_cast<const float4*>(pa + s0);
      const float4 a1 = *reinterpret_cast<const float4*>(pa + s0 + 4);
      const float4 b0 = *reinterpret_cast<const float4*>(pb + s0);
      const float4 b1 = *reinterpret_cast<const float4*>(pb + s0 + 4);
      cvt2(a0.x, a0.y, ha.x, la.x);
      cvt2(a0.z, a0.w, ha.y, la.y);
      cvt2(a1.x, a1.y, ha.z, la.z);
      cvt2(a1.z, a1.w, ha.w, la.w);
      cvt2(b0.x, b0.y, hb.x, lb.x);
      cvt2(b0.z, b0.w, hb.y, lb.y);
      cvt2(b1.x, b1.y, hb.z, lb.z);
      cvt2(b1.z, b1.w, hb.w, lb.w);
    }
    const bf16x8 h0 = __builtin_bit_cast(bf16x8, ha);
    const bf16x8 l0 = __builtin_bit_cast(bf16x8, la);
    const bf16x8 h1 = __builtin_bit_cast(bf16x8, hb);
    const bf16x8 l1 = __builtin_bit_cast(bf16x8, lb);
    d1[0][0] = __builtin_amdgcn_mfma_f32_16x16x32_bf16(h0, h0, d1[0][0], 0, 0, 0);
    d1[0][1] = __builtin_amdgcn_mfma_f32_16x16x32_bf16(h0, h1, d1[0][1], 0, 0, 0);
    d1[1][0] = __builtin_amdgcn_mfma_f32_16x16x32_bf16(h1, h0, d1[1][0], 0, 0, 0);
    d1[1][1] = __builtin_amdgcn_mfma_f32_16x16x32_bf16(h1, h1, d1[1][1], 0, 0, 0);
    d2[0][0] = __builtin_amdgcn_mfma_f32_16x16x32_bf16(h0, l0, d2[0][0], 0, 0, 0);
    d2[0][1] = __builtin_amdgcn_mfma_f32_16x16x32_bf16(h0, l1, d2[0][1], 0, 0, 0);
    d2[1][0] = __builtin_amdgcn_mfma_f32_16x16x32_bf16(h1, l0, d2[1][0], 0, 0, 0);
    d2[1][1] = __builtin_amdgcn_mfma_f32_16x16x32_bf16(h1, l1, d2[1][1], 0, 0, 0);
    d3[0][0] = __builtin_amdgcn_mfma_f32_16x16x32_bf16(l0, h0, d3[0][0], 0, 0, 0);
    d3[0][1] = __builtin_amdgcn_mfma_f32_16x16x32_bf16(l0, h1, d3[0][1], 0, 0, 0);
    d3[1][0] = __builtin_amdgcn_mfma_f32_16x16x32_bf16(l1, h0, d3[1][0], 0, 0, 0);
    d3[1][1] = __builtin_amdgcn_mfma_f32_16x16x32_bf16(l1, h1, d3[1][1], 0, 0, 0);
  }

  // ---- epilogue: combine D1+D2+D3, reduce over 4 waves (LDS, 1 barrier) ----
  __shared__ float mtmp[4 * 1056];    // 16896 B
#pragma unroll
  for (int i = 0; i < 2; ++i)
#pragma unroll
    for (int j = 0; j < 2; ++j) {
      const f32x4 s4 = d1[i][j] + d2[i][j] + d3[i][j];
#pragma unroll
      for (int r = 0; r < 4; ++r) {
        const int row = i * 16 + g * 4 + r;       // m89-verified C/D map
        const int cc  = j * 16 + col;
        mtmp[w * 1056 + row * 33 + cc] = s4[r];
      }
    }
  __syncthreads();

  const int e0 = tid * 4;
  float tmp[4];
#pragma unroll
  for (int u = 0; u < 4; ++u) {
    const int row = (e0 + u) >> 5;
    const int cc  = (e0 + u) & 31;
    float ss = 0.f;
#pragma unroll
    for (int ww = 0; ww < 4; ++ww) ss += mtmp[ww * 1056 + row * 33 + cc];
    tmp[u] = ss;
  }
  float4 o4;
  o4.x = tmp[0]; o4.y = tmp[1]; o4.z = tmp[2]; o4.w = tmp[3];
  *reinterpret_cast<float4*>(part + (size_t)bc * 1024 + e0) = o4;
}

// ---------------------------------------------------------------------------
// Kernel 2: reduce partials over c.  msum[b][e] = sum_c part[b*64+c][e]
// ---------------------------------------------------------------------------
__global__ __launch_bounds__(256) void reduce_c(const float* __restrict__ part,
                                                float* __restrict__ msum) {
  const int bid = blockIdx.x;                // 0..63
  const int b   = bid >> 2;
  const int e   = (bid & 3) * 256 + threadIdx.x;   // 0..1023
  const float* __restrict__ p = part + (size_t)b * 64 * 1024 + e;
  float s0 = 0.f, s1 = 0.f, s2 = 0.f, s3 = 0.f;
#pragma unroll
  for (int c = 0; c < 64; c += 4) {
    s0 += p[(size_t)(c + 0) * 1024];
    s1 += p[(size_t)(c + 1) * 1024];
    s2 += p[(size_t)(c + 2) * 1024];
    s3 += p[(size_t)(c + 3) * 1024];
  }
  msum[b * 1024 + e] = (s0 + s1) + (s2 + s3);
}

// ---------------------------------------------------------------------------
// Kernel 3: softmax over the BATCH axis. Output q-major: mq[b][q*32+k].
// ---------------------------------------------------------------------------
__global__ __launch_bounds__(256) void softmax_b(const float* __restrict__ msum,
                                                 float* __restrict__ mq) {
  const int e = blockIdx.x * 256 + threadIdx.x;    // q*32 + k
  float l[16];
  float mx = -3.4e38f;
#pragma unroll
  for (int b = 0; b < 16; ++b) {
    l[b] = msum[b * 1024 + e];
    mx = fmaxf(mx, l[b]);
  }
  float s = 0.f;
#pragma unroll
  for (int b = 0; b < 16; ++b) {
    l[b] = expf(l[b] - mx);
    s += l[b];
  }
  const float inv = 1.f / s;
#pragma unroll
  for (int b = 0; b < 16; ++b) mq[b * 1024 + e] = l[b] * inv;
}

// ---------------------------------------------------------------------------
// Kernel 4: PV — r19's counted-vmcnt MFMA skeleton + LDS-BOUNCED CONTIGUOUS
// STORES. All prior pv variants store 16 scattered 64B half-lines per instr
// (q varies across lanes, forced by the MFMA C/D map); the 6.3 TB/s copy
// stores full contiguous lines. This round: D frags -> obuf[32][132] in LDS
// (pad kills the worst write conflicts), then a copy-style pass emits
// 2 rows x 512 B contiguous per store instr (mirrors the stage reads).
// vmcnt counting unchanged: 4 loads + 4 stores per wave per chunk -> N=8
// steady, 4 at edges (stores issued before stage at loop bottom).
// LDS 2x16384 (in) + 16896 (obuf) = 49664 B -> 3 blocks/CU.
// Math/frag layout byte-identical to r18/r19 (validated, absmax 0.0625).
// ---------------------------------------------------------------------------
__global__ __launch_bounds__(256, 3) void pv(const float* __restrict__ xv,
                                             const float* __restrict__ mq,
                                             float* __restrict__ out) {
  const int bc = blockIdx.x;                  // b*64 + c
  const int b  = bc >> 6;
  const float* __restrict__ xvb = xv + (size_t)bc * (Tt * Ss);
  float* __restrict__ ob        = out + (size_t)bc * (Tt * Ss);

  const int tid  = threadIdx.x;
  const int w    = tid >> 6;                  // wave 0..3
  const int lane = tid & 63;
  const int col  = lane & 15;                 // frag column / M row
  const int g    = lane >> 4;                 // k-group (k = 8g..8g+7)

  __shared__ float ibuf[2][32 * 128];         // 2 x 16384 B
  __shared__ float obuf[32 * 132];            // 16896 B (row stride 132)

  // ---- M fragments (once per block) — r9/r16-validated ----
  bf16x8 mh[2], ml[2];
#pragma unroll
  for (int qf = 0; qf < 2; ++qf) {
    const float* mp = mq + b * 1024 + (qf * 16 + col) * 32 + g * 8;
    const float4 ma = *reinterpret_cast<const float4*>(mp);
    const float4 mb = *reinterpret_cast<const float4*>(mp + 4);
    uint4 h, l;
    cvt2(ma.x, ma.y, h.x, l.x);
    cvt2(ma.z, ma.w, h.y, l.y);
    cvt2(mb.x, mb.y, h.z, l.z);
    cvt2(mb.z, mb.w, h.w, l.w);
    mh[qf] = __builtin_bit_cast(bf16x8, h);
    ml[qf] = __builtin_bit_cast(bf16x8, l);
  }

  // stage chunk ch (128 floats at off = ch*128) into ibuf[buf]:
  // 1024 slots = 4 rounds x 256; slot v = row*32 + c4 (linear).
  auto stage = [&](int buf, int ch) {
    const int off = ch * 128;
#pragma unroll
    for (int round = 0; round < 4; ++round) {
      const int v   = round * 256 + tid;
      const int row = v >> 5;
      const int c4  = v & 31;
      gload16(xvb + row * Ss + off + c4 * 4,
              &ibuf[buf][(round * 256 + w * 64) * 4]);
    }
  };

  stage(0, 0);
  stage(1, 1);

#pragma unroll
  for (int ch = 0; ch < 6; ++ch) {
    // counted wait: chunk ch's loads done; newer loads/stores stay in flight.
    if (ch == 0 || ch == 5) {
      asm volatile("s_waitcnt vmcnt(4)" ::: "memory");
    } else {
      asm volatile("s_waitcnt vmcnt(8)" ::: "memory");
    }
    __builtin_amdgcn_sched_barrier(0);
    __builtin_amdgcn_s_barrier();               // all waves' ch-loads landed

    const float* __restrict__ lbuf = ibuf[ch & 1];
#pragma unroll
    for (int fi = 0; fi < 2; ++fi) {
      const int sf = 2 * w + fi;                // this wave's frag
      float f8[8];
#pragma unroll
      for (int j = 0; j < 8; ++j)
        f8[j] = lbuf[(8 * g + j) * 128 + sf * 16 + col];
      uint4 hh, lv;
      cvt2(f8[0], f8[1], hh.x, lv.x);
      cvt2(f8[2], f8[3], hh.y, lv.y);
      cvt2(f8[4], f8[5], hh.z, lv.z);
      cvt2(f8[6], f8[7], hh.w, lv.w);
      const bf16x8 vh = __builtin_bit_cast(bf16x8, hh);
      const bf16x8 vl = __builtin_bit_cast(bf16x8, lv);
#pragma unroll
      for (int qf = 0; qf < 2; ++qf) {
        f32x4 d = {0.f, 0.f, 0.f, 0.f};
        d = __builtin_amdgcn_mfma_f32_16x16x32_bf16(vl, mh[qf], d, 0, 0, 0);
        d = __builtin_amdgcn_mfma_f32_16x16x32_bf16(vh, ml[qf], d, 0, 0, 0);
        d = __builtin_amdgcn_mfma_f32_16x16x32_bf16(vh, mh[qf], d, 0, 0, 0);
        // D[s][q]: lane(col,g) regs = chunk-local s = sf*16+4g..+3 of q-row
        float4 o4;
        o4.x = d[0]; o4.y = d[1]; o4.z = d[2]; o4.w = d[3];
        *reinterpret_cast<float4*>(
            &obuf[(qf * 16 + col) * 132 + sf * 16 + 4 * g]) = o4;
      }
    }
    asm volatile("s_waitcnt lgkmcnt(0)" ::: "memory");   // obuf writes + lbuf reads done
    __builtin_amdgcn_sched_barrier(0);
    __builtin_amdgcn_s_barrier();               // obuf complete; ibuf free

    // ---- copy-out: contiguous stores, 2 rows x 512 B per instr ----
    const int off = ch * 128;
#pragma unroll
    for (int round = 0; round < 4; ++round) {
      const int v   = round * 256 + tid;        // slot = row*32 + c4
      const int row = v >> 5;
      const int c4  = v & 31;
      const float4 o = *reinterpret_cast<const float4*>(&obuf[row * 132 + c4 * 4]);
      *reinterpret_cast<float4*>(ob + row * Ss + off + c4 * 4) = o;
    }
    if (ch < 4) stage(ch & 1, ch + 2);          // keep next loads in flight
  }

  // ---- tail frag: s = 768..783, direct from global (wave 3 only) ----
  if (w == 3) {
    float f8[8];
#pragma unroll
    for (int j = 0; j < 8; ++j)
      f8[j] = xvb[(size_t)(8 * g + j) * Ss + 768 + col];
    uint4 hh, lv;
    cvt2(f8[0], f8[1], hh.x, lv.x);
    cvt2(f8[2], f8[3], hh.y, lv.y);
    cvt2(f8[4], f8[5], hh.z, lv.z);
    cvt2(f8[6], f8[7], hh.w, lv.w);
    const bf16x8 vh = __builtin_bit_cast(bf16x8, hh);
    const bf16x8 vl = __builtin_bit_cast(bf16x8, lv);
#pragma unroll
    for (int qf = 0; qf < 2; ++qf) {
      f32x4 d = {0.f, 0.f, 0.f, 0.f};
      d = __builtin_amdgcn_mfma_f32_16x16x32_bf16(vl, mh[qf], d, 0, 0, 0);
      d = __builtin_amdgcn_mfma_f32_16x16x32_bf16(vh, ml[qf], d, 0, 0, 0);
      d = __builtin_amdgcn_mfma_f32_16x16x32_bf16(vh, mh[qf], d, 0, 0, 0);
      float4 o4;
      o4.x = d[0]; o4.y = d[1]; o4.z = d[2]; o4.w = d[3];
      *reinterpret_cast<float4*>(ob + (size_t)(qf * 16 + col) * Ss + 768 + 4 * g) = o4;
    }
  }
}

}  // namespace

extern "C" void kernel_launch(void* const* d_in, const int* in_sizes, int n_in,
                              void* d_out, int out_size, void* d_ws, size_t ws_size,
                              hipStream_t stream) {
  const float* x  = (const float*)d_in[0];
  const float* xv = (const float*)d_in[1];
  float* out = (float*)d_out;

  // workspace (fp32), ~4.2 MiB total:
  float* part = (float*)d_ws;            // 1024 x 1024
  float* msum = part + 1024 * 1024;      // 16 x 1024
  float* mq   = msum + 16 * 1024;        // 16 x 1024 (q-major softmax weights)

  gram_partial<<<dim3(1024), dim3(256), 0, stream>>>(x, part);
  reduce_c<<<dim3(64), dim3(256), 0, stream>>>(part, msum);
  softmax_b<<<dim3(4), dim3(256), 0, stream>>>(msum, mq);
  pv<<<dim3(1024), dim3(256), 0, stream>>>(xv, mq, out);
}